// Round 1
// baseline (3516.572 us; speedup 1.0000x reference)
//
#include <hip/hip_runtime.h>

// Transformer_67748814127473 — round 0: fp32 correctness-first baseline.
// B=8, T=1024, N=2048, E=256, L=4. All fp32.
// ws layout (floats): H[4M] Q[4M] K[4M] V[4M] BE[2048]  => ~64MB.

#define BB 8
#define TT 1024
#define NN 2048
#define EE 256
#define LL 4

// ---------------- per-batch even-row base vector ----------------
// BE[b,e] = sum_f action_set[b,f]*W_embed[f,e] + W_embed[651,e] + b_embed[e]
__global__ __launch_bounds__(256) void base_even_k(
    const float* __restrict__ aset, const float* __restrict__ We,
    const float* __restrict__ be, float* __restrict__ BE)
{
    int b = blockIdx.x; int e = threadIdx.x;
    __shared__ float as[640];
    for (int i = e; i < 640; i += 256) as[i] = aset[b*640 + i];
    __syncthreads();
    float s = We[651*EE + e] + be[e];
    for (int f = 0; f < 640; ++f) s = fmaf(as[f], We[f*EE + e], s);
    BE[b*EE + e] = s;
}

// ---------------- embedding: H[b,n,:] ----------------
// even n: BE[b] ; odd n=2t+1: 10 ctx_action terms + reward term + one-term
// both: + (n+1)*W_embed[652] + wpe[n]
__global__ __launch_bounds__(256) void embed_k(
    const float* __restrict__ BE, const float* __restrict__ ca,
    const float* __restrict__ cr, const float* __restrict__ We,
    const float* __restrict__ be, const float* __restrict__ wpe,
    float* __restrict__ H)
{
    int rb = blockIdx.x;              // b*N + n
    int b = rb >> 11; int n = rb & (NN-1);
    int e = threadIdx.x;
    float h;
    if ((n & 1) == 0) {
        h = BE[b*EE + e];
    } else {
        int t = n >> 1;
        h = We[651*EE + e] + be[e];
        const float* cap = ca + (size_t)(b*TT + t)*10;
        #pragma unroll
        for (int i = 0; i < 10; ++i) h = fmaf(cap[i], We[(640+i)*EE + e], h);
        h = fmaf(cr[b*TT + t], We[650*EE + e], h);
    }
    h = fmaf((float)(n + 1), We[652*EE + e], h);
    h += wpe[(size_t)n*EE + e];
    H[(size_t)rb*EE + e] = h;
}

// ---------------- generic 64x64-tile fp32 GEMM: C = act(A@W + bias) + Res ----
// A: [16384,256] row-major, W: [256,256] row-major, C: [16384,256]
template<int RELU, int BIAS, int RES>
__global__ __launch_bounds__(256) void gemm_k(
    const float* __restrict__ A, const float* __restrict__ Wm,
    const float* __restrict__ bias, const float* __restrict__ Res,
    float* __restrict__ C)
{
    __shared__ float As[16][64];   // [k][row]
    __shared__ float Ws[16][64];   // [k][col]
    int tid = threadIdx.x;
    int tr = tid >> 4, tc = tid & 15;
    int row0 = blockIdx.x * 64, col0 = blockIdx.y * 64;
    int lr = tid >> 2, lk = (tid & 3) * 4;
    int wk = tid >> 4, wc = (tid & 15) * 4;
    float acc[4][4] = {};
    for (int k0 = 0; k0 < EE; k0 += 16) {
        float4 av = *(const float4*)&A[(size_t)(row0 + lr)*EE + k0 + lk];
        float4 wv = *(const float4*)&Wm[(size_t)(k0 + wk)*EE + col0 + wc];
        __syncthreads();
        As[lk+0][lr] = av.x; As[lk+1][lr] = av.y; As[lk+2][lr] = av.z; As[lk+3][lr] = av.w;
        *(float4*)&Ws[wk][wc] = wv;
        __syncthreads();
        #pragma unroll
        for (int kk = 0; kk < 16; ++kk) {
            float4 a4 = *(const float4*)&As[kk][tr*4];
            float4 b4 = *(const float4*)&Ws[kk][tc*4];
            float av_[4] = {a4.x, a4.y, a4.z, a4.w};
            float bv_[4] = {b4.x, b4.y, b4.z, b4.w};
            #pragma unroll
            for (int i = 0; i < 4; ++i)
                #pragma unroll
                for (int j = 0; j < 4; ++j)
                    acc[i][j] = fmaf(av_[i], bv_[j], acc[i][j]);
        }
    }
    #pragma unroll
    for (int i = 0; i < 4; ++i) {
        int r = row0 + tr*4 + i;
        size_t cb = (size_t)r*EE + col0 + tc*4;
        float v[4];
        #pragma unroll
        for (int j = 0; j < 4; ++j) {
            float x = acc[i][j];
            if (BIAS) x += bias[col0 + tc*4 + j];
            if (RELU) x = fmaxf(x, 0.f);
            if (RES)  x += Res[cb + j];
            v[j] = x;
        }
        float4 o; o.x=v[0]; o.y=v[1]; o.z=v[2]; o.w=v[3];
        *(float4*)&C[cb] = o;
    }
}

// ---------------- fused causal relu-attention ----------------
// X[b,i,:] = H[b,i,:] + (1/(i+1)) * sum_{j<=i} relu(q_i . k_j) * v_j
// block: one 64-row i-tile of one batch; loops over j-tiles <= it.
__global__ __launch_bounds__(256) void attn_k(
    const float* __restrict__ Q, const float* __restrict__ K,
    const float* __restrict__ V, const float* __restrict__ H,
    float* __restrict__ X)
{
    int it = blockIdx.x;   // 0..31
    int b  = blockIdx.y;   // 0..7
    int row0 = it * 64;
    const float* Qb = Q + (size_t)b*NN*EE;
    const float* Kb = K + (size_t)b*NN*EE;
    const float* Vb = V + (size_t)b*NN*EE;

    __shared__ float Ts[16][64];    // q chunk [k][row]
    __shared__ float Us[16][64];    // k chunk [k][col]
    __shared__ float Ss[64][64];    // S transposed: Ss[j][i]
    __shared__ float Vs[16][256];   // v chunk [j][e]

    int tid = threadIdx.x;
    int tr = tid >> 4, tc = tid & 15;
    int lr = tid >> 2, lk = (tid & 3) * 4;
    int vr = tid >> 4, vc = (tid & 15) * 16;

    float o[4][4][4] = {};   // [u][g][w] : row tr*4+u, col tc*4+g*64+w

    for (int jt = 0; jt <= it; ++jt) {
        // ---- phase 1: S = Q_it . K_jt^T  (64x64), K-dim streamed in 16s ----
        float s[4][4] = {};
        for (int k0 = 0; k0 < EE; k0 += 16) {
            float4 qv = *(const float4*)&Qb[(size_t)(row0 + lr)*EE + k0 + lk];
            float4 kv = *(const float4*)&Kb[(size_t)(jt*64 + lr)*EE + k0 + lk];
            __syncthreads();
            Ts[lk+0][lr]=qv.x; Ts[lk+1][lr]=qv.y; Ts[lk+2][lr]=qv.z; Ts[lk+3][lr]=qv.w;
            Us[lk+0][lr]=kv.x; Us[lk+1][lr]=kv.y; Us[lk+2][lr]=kv.z; Us[lk+3][lr]=kv.w;
            __syncthreads();
            #pragma unroll
            for (int kk = 0; kk < 16; ++kk) {
                float4 a4 = *(const float4*)&Ts[kk][tr*4];
                float4 b4 = *(const float4*)&Us[kk][tc*4];
                float av_[4] = {a4.x, a4.y, a4.z, a4.w};
                float bv_[4] = {b4.x, b4.y, b4.z, b4.w};
                #pragma unroll
                for (int i = 0; i < 4; ++i)
                    #pragma unroll
                    for (int j = 0; j < 4; ++j)
                        s[i][j] = fmaf(av_[i], bv_[j], s[i][j]);
            }
        }
        __syncthreads();
        // relu + causal mask (only intra-tile when jt==it) + store transposed
        #pragma unroll
        for (int i = 0; i < 4; ++i)
            #pragma unroll
            for (int j = 0; j < 4; ++j) {
                float v = fmaxf(s[i][j], 0.f);
                if (jt == it && (tc*4 + j) > (tr*4 + i)) v = 0.f;
                Ss[tc*4+j][tr*4+i] = v;
            }
        __syncthreads();
        // ---- phase 2: O += S . V_jt, V streamed in 16-row chunks ----
        for (int j0 = 0; j0 < 64; j0 += 16) {
            const float* vp = &Vb[(size_t)(jt*64 + j0 + vr)*EE + vc];
            float4 v0 = *(const float4*)(vp + 0);
            float4 v1 = *(const float4*)(vp + 4);
            float4 v2 = *(const float4*)(vp + 8);
            float4 v3 = *(const float4*)(vp + 12);
            __syncthreads();
            *(float4*)&Vs[vr][vc+ 0] = v0;
            *(float4*)&Vs[vr][vc+ 4] = v1;
            *(float4*)&Vs[vr][vc+ 8] = v2;
            *(float4*)&Vs[vr][vc+12] = v3;
            __syncthreads();
            #pragma unroll
            for (int j = 0; j < 16; ++j) {
                float4 s4 = *(const float4*)&Ss[j0+j][tr*4];
                float sv[4] = {s4.x, s4.y, s4.z, s4.w};
                #pragma unroll
                for (int g = 0; g < 4; ++g) {
                    float4 vv = *(const float4*)&Vs[j][tc*4 + g*64];
                    float vw[4] = {vv.x, vv.y, vv.z, vv.w};
                    #pragma unroll
                    for (int u = 0; u < 4; ++u)
                        #pragma unroll
                        for (int w = 0; w < 4; ++w)
                            o[u][g][w] = fmaf(sv[u], vw[w], o[u][g][w]);
                }
            }
        }
        __syncthreads();
    }
    // epilogue: X = H + o/(i+1)
    #pragma unroll
    for (int u = 0; u < 4; ++u) {
        int r = row0 + tr*4 + u;
        float scale = 1.0f / (float)(r + 1);
        size_t base = ((size_t)b*NN + r)*EE;
        #pragma unroll
        for (int g = 0; g < 4; ++g) {
            int col = tc*4 + g*64;
            float4 hv = *(const float4*)&H[base + col];
            float4 ov;
            ov.x = hv.x + o[u][g][0]*scale;
            ov.y = hv.y + o[u][g][1]*scale;
            ov.z = hv.z + o[u][g][2]*scale;
            ov.w = hv.w + o[u][g][3]*scale;
            *(float4*)&X[base + col] = ov;
        }
    }
}

// ---------------- LayerNorm (one block per row) ----------------
__global__ __launch_bounds__(256) void ln_k(
    const float* __restrict__ Xin, const float* __restrict__ g,
    const float* __restrict__ bta, float* __restrict__ Hout)
{
    int row = blockIdx.x;
    int e = threadIdx.x;
    float x = Xin[(size_t)row*EE + e];
    float s = x, s2 = x*x;
    #pragma unroll
    for (int off = 32; off > 0; off >>= 1) {
        s  += __shfl_down(s, off);
        s2 += __shfl_down(s2, off);
    }
    __shared__ float red[8];
    int w = e >> 6;
    if ((e & 63) == 0) { red[w] = s; red[4+w] = s2; }
    __syncthreads();
    float tot  = red[0] + red[1] + red[2] + red[3];
    float tot2 = red[4] + red[5] + red[6] + red[7];
    float mean = tot * (1.0f/256.0f);
    float var  = tot2 * (1.0f/256.0f) - mean*mean;
    float inv  = 1.0f / sqrtf(var + 1e-5f);
    Hout[(size_t)row*EE + e] = (x - mean) * inv * g[e] + bta[e];
}

// ---------------- prediction head (even rows only) ----------------
__global__ __launch_bounds__(256) void pred_k(
    const float* __restrict__ H, const float* __restrict__ Wp,
    const float* __restrict__ bp, float* __restrict__ out)
{
    int bt = blockIdx.x;           // b*1024 + t
    int b = bt >> 10, t = bt & 1023;
    size_t row = (size_t)b*NN + 2*t;
    __shared__ float hs[256];
    __shared__ float pr[16][16];
    int tid = threadIdx.x;
    hs[tid] = H[row*EE + tid];
    __syncthreads();
    int c = tid & 15, seg = tid >> 4;
    float p = 0.f;
    if (c < 10) {
        #pragma unroll
        for (int e2 = 0; e2 < 16; ++e2)
            p = fmaf(hs[seg*16 + e2], Wp[(seg*16 + e2)*10 + c], p);
    }
    pr[seg][c] = p;
    __syncthreads();
    if (tid < 10) {
        float sacc = bp[tid];
        #pragma unroll
        for (int k2 = 0; k2 < 16; ++k2) sacc += pr[k2][tid];
        out[(size_t)bt*10 + tid] = sacc;
    }
}

extern "C" void kernel_launch(void* const* d_in, const int* in_sizes, int n_in,
                              void* d_out, int out_size, void* d_ws, size_t ws_size,
                              hipStream_t stream)
{
    const float* action_set = (const float*)d_in[1];
    const float* ctx_act    = (const float*)d_in[2];
    const float* ctx_rew    = (const float*)d_in[3];
    const float* W_embed    = (const float*)d_in[4];
    const float* b_embed    = (const float*)d_in[5];
    const float* wpe        = (const float*)d_in[6];
    const float* Wq         = (const float*)d_in[7];
    const float* Wk         = (const float*)d_in[8];
    const float* Wv         = (const float*)d_in[9];
    const float* ln1g       = (const float*)d_in[10];
    const float* ln1b       = (const float*)d_in[11];
    const float* W1         = (const float*)d_in[12];
    const float* b1         = (const float*)d_in[13];
    const float* W2         = (const float*)d_in[14];
    const float* b2         = (const float*)d_in[15];
    const float* ln2g       = (const float*)d_in[16];
    const float* ln2b       = (const float*)d_in[17];
    const float* Wp         = (const float*)d_in[18];
    const float* bp         = (const float*)d_in[19];
    float* out = (float*)d_out;

    float* ws = (float*)d_ws;
    const size_t SZ = (size_t)BB*NN*EE;   // 4,194,304 floats
    float* Hb = ws;
    float* Qb = ws + SZ;
    float* Kb = ws + 2*SZ;
    float* Vb = ws + 3*SZ;
    float* BE = ws + 4*SZ;

    base_even_k<<<BB, 256, 0, stream>>>(action_set, W_embed, b_embed, BE);
    embed_k<<<BB*NN, 256, 0, stream>>>(BE, ctx_act, ctx_rew, W_embed, b_embed, wpe, Hb);

    dim3 gg(BB*NN/64, EE/64);
    for (int l = 0; l < LL; ++l) {
        gemm_k<0,0,0><<<gg, 256, 0, stream>>>(Hb, Wq + (size_t)l*EE*EE, nullptr, nullptr, Qb);
        gemm_k<0,0,0><<<gg, 256, 0, stream>>>(Hb, Wk + (size_t)l*EE*EE, nullptr, nullptr, Kb);
        gemm_k<0,0,0><<<gg, 256, 0, stream>>>(Hb, Wv + (size_t)l*EE*EE, nullptr, nullptr, Vb);
        // writes X into Qb (each block writes only its own 64 rows, which no
        // other block reads from Q) — safe in-place reuse.
        attn_k<<<dim3(NN/64, BB), 256, 0, stream>>>(Qb, Kb, Vb, Hb, Qb);
        ln_k<<<BB*NN, 256, 0, stream>>>(Qb, ln1g + l*EE, ln1b + l*EE, Hb);
        gemm_k<1,1,0><<<gg, 256, 0, stream>>>(Hb, W1 + (size_t)l*EE*EE, b1 + l*EE, nullptr, Kb);
        gemm_k<0,1,1><<<gg, 256, 0, stream>>>(Kb, W2 + (size_t)l*EE*EE, b2 + l*EE, Hb, Vb);
        ln_k<<<BB*NN, 256, 0, stream>>>(Vb, ln2g + l*EE, ln2b + l*EE, Hb);
    }
    pred_k<<<BB*TT, 256, 0, stream>>>(Hb, Wp, bp, out);
}

// Round 2
// 1196.246 us; speedup vs baseline: 2.9397x; 2.9397x over previous
//
#include <hip/hip_runtime.h>

// Transformer_67748814127473 — round 1: bf16-MFMA attention.
// B=8, T=1024, N=2048, E=256, L=4.
// ws (floats): Hb[4M] X[4M] | shorts: Qbf[4M] Kbf[4M] Vt[4M] | BE[2048]f

#define BB 8
#define TT 1024
#define NN 2048
#define EE 256
#define LL 4

typedef __attribute__((ext_vector_type(8))) short short8;
typedef __attribute__((ext_vector_type(4))) float f32x4;

__device__ inline ushort f2b(float f) {
    union { float f; unsigned u; } x; x.f = f;
    unsigned u = x.u;
    return (ushort)((u + 0x7fffu + ((u >> 16) & 1u)) >> 16);
}

// ---------------- per-batch even-row base vector ----------------
__global__ __launch_bounds__(256) void base_even_k(
    const float* __restrict__ aset, const float* __restrict__ We,
    const float* __restrict__ be, float* __restrict__ BE)
{
    int b = blockIdx.x; int e = threadIdx.x;
    __shared__ float as[640];
    for (int i = e; i < 640; i += 256) as[i] = aset[b*640 + i];
    __syncthreads();
    float s = We[651*EE + e] + be[e];
    for (int f = 0; f < 640; ++f) s = fmaf(as[f], We[f*EE + e], s);
    BE[b*EE + e] = s;
}

// ---------------- embedding ----------------
__global__ __launch_bounds__(256) void embed_k(
    const float* __restrict__ BE, const float* __restrict__ ca,
    const float* __restrict__ cr, const float* __restrict__ We,
    const float* __restrict__ be, const float* __restrict__ wpe,
    float* __restrict__ H)
{
    int rb = blockIdx.x;
    int b = rb >> 11; int n = rb & (NN-1);
    int e = threadIdx.x;
    float h;
    if ((n & 1) == 0) {
        h = BE[b*EE + e];
    } else {
        int t = n >> 1;
        h = We[651*EE + e] + be[e];
        const float* cap = ca + (size_t)(b*TT + t)*10;
        #pragma unroll
        for (int i = 0; i < 10; ++i) h = fmaf(cap[i], We[(640+i)*EE + e], h);
        h = fmaf(cr[b*TT + t], We[650*EE + e], h);
    }
    h = fmaf((float)(n + 1), We[652*EE + e], h);
    h += wpe[(size_t)n*EE + e];
    H[(size_t)rb*EE + e] = h;
}

// ---------------- 64x64-tile fp32 GEMM: C = act(A@W + bias) + Res ----------
// OUTB=1: C is bf16 (ushort*), else fp32 (float*).
template<int RELU, int BIAS, int RES, int OUTB>
__global__ __launch_bounds__(256) void gemm_k(
    const float* __restrict__ A, const float* __restrict__ Wm,
    const float* __restrict__ bias, const float* __restrict__ Res,
    void* __restrict__ Cv)
{
    __shared__ float As[16][64];
    __shared__ float Ws[16][64];
    int tid = threadIdx.x;
    int tr = tid >> 4, tc = tid & 15;
    int row0 = blockIdx.x * 64, col0 = blockIdx.y * 64;
    int lr = tid >> 2, lk = (tid & 3) * 4;
    int wk = tid >> 4, wc = (tid & 15) * 4;
    float acc[4][4] = {};
    for (int k0 = 0; k0 < EE; k0 += 16) {
        float4 av = *(const float4*)&A[(size_t)(row0 + lr)*EE + k0 + lk];
        float4 wv = *(const float4*)&Wm[(size_t)(k0 + wk)*EE + col0 + wc];
        __syncthreads();
        As[lk+0][lr] = av.x; As[lk+1][lr] = av.y; As[lk+2][lr] = av.z; As[lk+3][lr] = av.w;
        *(float4*)&Ws[wk][wc] = wv;
        __syncthreads();
        #pragma unroll
        for (int kk = 0; kk < 16; ++kk) {
            float4 a4 = *(const float4*)&As[kk][tr*4];
            float4 b4 = *(const float4*)&Ws[kk][tc*4];
            float av_[4] = {a4.x, a4.y, a4.z, a4.w};
            float bv_[4] = {b4.x, b4.y, b4.z, b4.w};
            #pragma unroll
            for (int i = 0; i < 4; ++i)
                #pragma unroll
                for (int j = 0; j < 4; ++j)
                    acc[i][j] = fmaf(av_[i], bv_[j], acc[i][j]);
        }
    }
    #pragma unroll
    for (int i = 0; i < 4; ++i) {
        int r = row0 + tr*4 + i;
        size_t cb = (size_t)r*EE + col0 + tc*4;
        float v[4];
        #pragma unroll
        for (int j = 0; j < 4; ++j) {
            float x = acc[i][j];
            if (BIAS) x += bias[col0 + tc*4 + j];
            if (RELU) x = fmaxf(x, 0.f);
            if (RES)  x += Res[cb + j];
            v[j] = x;
        }
        if (OUTB) {
            ushort4 o;
            o.x = f2b(v[0]); o.y = f2b(v[1]); o.z = f2b(v[2]); o.w = f2b(v[3]);
            *(ushort4*)&((ushort*)Cv)[cb] = o;
        } else {
            float4 o; o.x=v[0]; o.y=v[1]; o.z=v[2]; o.w=v[3];
            *(float4*)&((float*)Cv)[cb] = o;
        }
    }
}

// ---------------- V transpose+cast: V fp32 [16384][256] -> Vt bf16 [B][E][N] --
__global__ __launch_bounds__(256) void vtrans_k(
    const float* __restrict__ V, ushort* __restrict__ Vt)
{
    int tn = blockIdx.x;           // 0..255 (64-row n tiles over 16384)
    int te = blockIdx.y;           // 0..3  (64-col e tiles)
    int b = (tn * 64) >> 11;
    int n0 = (tn * 64) & (NN - 1);
    int e0 = te * 64;
    __shared__ ushort Tt[64][68];
    int t = threadIdx.x;
    int r = t >> 4, c4 = (t & 15) * 4;
    #pragma unroll
    for (int it = 0; it < 4; ++it) {
        int n = r + it*16;
        float4 v = *(const float4*)&V[(size_t)(tn*64 + n)*EE + e0 + c4];
        Tt[n][c4+0] = f2b(v.x); Tt[n][c4+1] = f2b(v.y);
        Tt[n][c4+2] = f2b(v.z); Tt[n][c4+3] = f2b(v.w);
    }
    __syncthreads();
    #pragma unroll
    for (int it = 0; it < 4; ++it) {
        int e = r + it*16;
        ushort4 o;
        o.x = Tt[c4+0][e]; o.y = Tt[c4+1][e];
        o.z = Tt[c4+2][e]; o.w = Tt[c4+3][e];
        *(ushort4*)&Vt[((size_t)(b*EE + e0 + e))*NN + n0 + c4] = o;
    }
}

// ---------------- bf16 MFMA causal relu-attention ----------------
// X[b,i,:] = H[b,i,:] + (1/(i+1)) * sum_{j<=i} relu(q_i.k_j) * v_j
// Block: pair of 32-row i-tiles (p, 63-p) of one batch -> uniform 66 units.
// 4 waves: QK^T S[32][32] split 2x2; PV O[32][256] split by 64-col quarters.
__global__ __launch_bounds__(256) void attn_k(
    const ushort* __restrict__ Qb, const ushort* __restrict__ Kb,
    const ushort* __restrict__ Vt, const float* __restrict__ H,
    float* __restrict__ X)
{
    int blk = blockIdx.x;            // p*8 + b
    int p = blk >> 3, b = blk & 7;
    int tid = threadIdx.x;
    int w = tid >> 6;
    int l = tid & 63;
    int lr = l & 15, lg = l >> 4;
    int rsub = (w >> 1) * 16;        // S row-subtile for this wave
    int csub = (w & 1) * 16;         // S col-subtile for this wave
    __shared__ __align__(16) ushort Sl[32*32];   // swizzled S tile (2 KB)
    char* Sb = (char*)Sl;

    const ushort* Qbb = Qb + (size_t)b*NN*EE;
    const ushort* Kbb = Kb + (size_t)b*NN*EE;
    const ushort* Vtb = Vt + (size_t)b*EE*NN;

    for (int half = 0; half < 2; ++half) {
        int z = half ? (63 - p) : p;
        int row0 = z * 32;
        // Q A-frags in registers: rows rsub+lr, k = kc*32 + lg*8 .. +7
        short8 qa[8];
        #pragma unroll
        for (int kc = 0; kc < 8; ++kc)
            qa[kc] = *(const short8*)&Qbb[(size_t)(row0 + rsub + lr)*EE + kc*32 + lg*8];
        f32x4 oacc[2][4];
        #pragma unroll
        for (int rs = 0; rs < 2; ++rs)
            #pragma unroll
            for (int cs = 0; cs < 4; ++cs)
                oacc[rs][cs] = (f32x4){0.f,0.f,0.f,0.f};

        for (int jt = 0; jt <= z; ++jt) {
            // ---- QK^T: this wave's 16x16 subtile of S ----
            f32x4 s0 = {0.f,0.f,0.f,0.f}, s1 = {0.f,0.f,0.f,0.f};
            const ushort* kp = &Kbb[(size_t)(jt*32 + csub + lr)*EE + lg*8];
            #pragma unroll
            for (int kc = 0; kc < 8; kc += 2) {
                short8 k0 = *(const short8*)(kp + kc*32);
                short8 k1 = *(const short8*)(kp + kc*32 + 32);
                s0 = __builtin_amdgcn_mfma_f32_16x16x32_bf16(qa[kc],   k0, s0, 0, 0, 0);
                s1 = __builtin_amdgcn_mfma_f32_16x16x32_bf16(qa[kc+1], k1, s1, 0, 0, 0);
            }
            f32x4 s = s0 + s1;
            __syncthreads();   // all waves done reading previous S
            // relu + causal mask + swizzled bf16 store (C: row=4*lg+r, col=lr)
            #pragma unroll
            for (int r = 0; r < 4; ++r) {
                int il = rsub + lg*4 + r;          // local i in [0,32)
                int jl = csub + lr;                // local j in [0,32)
                float v = s[r] > 0.f ? s[r] : 0.f;
                if (jt*32 + jl > row0 + il) v = 0.f;
                *(ushort*)(Sb + il*64 + ((jl*2) ^ ((il & 3) << 4))) = f2b(v);
            }
            __syncthreads();
            // ---- PV: O[32][w*64..w*64+64) += S @ V_jt ----
            int i0 = lr;
            short8 sa0 = *(const short8*)(Sb + i0*64      + ((lg*16) ^ ((i0 & 3) << 4)));
            short8 sa1 = *(const short8*)(Sb + (16+i0)*64 + ((lg*16) ^ ((i0 & 3) << 4)));
            const ushort* vp = &Vtb[(size_t)(w*64 + lr)*NN + jt*32 + lg*8];
            #pragma unroll
            for (int cs = 0; cs < 4; ++cs) {
                short8 vb = *(const short8*)(vp + (size_t)(cs*16)*NN);
                oacc[0][cs] = __builtin_amdgcn_mfma_f32_16x16x32_bf16(sa0, vb, oacc[0][cs], 0, 0, 0);
                oacc[1][cs] = __builtin_amdgcn_mfma_f32_16x16x32_bf16(sa1, vb, oacc[1][cs], 0, 0, 0);
            }
        }
        // ---- epilogue: X = H + O/(i+1) ----
        #pragma unroll
        for (int rs = 0; rs < 2; ++rs)
            #pragma unroll
            for (int r = 0; r < 4; ++r) {
                int ig = row0 + rs*16 + lg*4 + r;
                float sc = 1.0f / (float)(ig + 1);
                size_t base = ((size_t)b*NN + ig)*EE + w*64 + lr;
                #pragma unroll
                for (int cs = 0; cs < 4; ++cs)
                    X[base + cs*16] = H[base + cs*16] + oacc[rs][cs][r] * sc;
            }
    }
}

// ---------------- LayerNorm (one block per row; in-place safe) ----------------
__global__ __launch_bounds__(256) void ln_k(
    const float* __restrict__ Xin, const float* __restrict__ g,
    const float* __restrict__ bta, float* __restrict__ Hout)
{
    int row = blockIdx.x;
    int e = threadIdx.x;
    float x = Xin[(size_t)row*EE + e];
    float s = x, s2 = x*x;
    #pragma unroll
    for (int off = 32; off > 0; off >>= 1) {
        s  += __shfl_down(s, off);
        s2 += __shfl_down(s2, off);
    }
    __shared__ float red[8];
    int w = e >> 6;
    if ((e & 63) == 0) { red[w] = s; red[4+w] = s2; }
    __syncthreads();
    float tot  = red[0] + red[1] + red[2] + red[3];
    float tot2 = red[4] + red[5] + red[6] + red[7];
    float mean = tot * (1.0f/256.0f);
    float var  = tot2 * (1.0f/256.0f) - mean*mean;
    float inv  = 1.0f / sqrtf(var + 1e-5f);
    Hout[(size_t)row*EE + e] = (x - mean) * inv * g[e] + bta[e];
}

// ---------------- prediction head (even rows only) ----------------
__global__ __launch_bounds__(256) void pred_k(
    const float* __restrict__ H, const float* __restrict__ Wp,
    const float* __restrict__ bp, float* __restrict__ out)
{
    int bt = blockIdx.x;
    int b = bt >> 10, t = bt & 1023;
    size_t row = (size_t)b*NN + 2*t;
    __shared__ float hs[256];
    __shared__ float pr[16][16];
    int tid = threadIdx.x;
    hs[tid] = H[row*EE + tid];
    __syncthreads();
    int c = tid & 15, seg = tid >> 4;
    float p = 0.f;
    if (c < 10) {
        #pragma unroll
        for (int e2 = 0; e2 < 16; ++e2)
            p = fmaf(hs[seg*16 + e2], Wp[(seg*16 + e2)*10 + c], p);
    }
    pr[seg][c] = p;
    __syncthreads();
    if (tid < 10) {
        float sacc = bp[tid];
        #pragma unroll
        for (int k2 = 0; k2 < 16; ++k2) sacc += pr[k2][tid];
        out[(size_t)bt*10 + tid] = sacc;
    }
}

extern "C" void kernel_launch(void* const* d_in, const int* in_sizes, int n_in,
                              void* d_out, int out_size, void* d_ws, size_t ws_size,
                              hipStream_t stream)
{
    const float* action_set = (const float*)d_in[1];
    const float* ctx_act    = (const float*)d_in[2];
    const float* ctx_rew    = (const float*)d_in[3];
    const float* W_embed    = (const float*)d_in[4];
    const float* b_embed    = (const float*)d_in[5];
    const float* wpe        = (const float*)d_in[6];
    const float* Wq         = (const float*)d_in[7];
    const float* Wk         = (const float*)d_in[8];
    const float* Wv         = (const float*)d_in[9];
    const float* ln1g       = (const float*)d_in[10];
    const float* ln1b       = (const float*)d_in[11];
    const float* W1         = (const float*)d_in[12];
    const float* b1         = (const float*)d_in[13];
    const float* W2         = (const float*)d_in[14];
    const float* b2         = (const float*)d_in[15];
    const float* ln2g       = (const float*)d_in[16];
    const float* ln2b       = (const float*)d_in[17];
    const float* Wp         = (const float*)d_in[18];
    const float* bp         = (const float*)d_in[19];
    float* out = (float*)d_out;

    float* ws = (float*)d_ws;
    const size_t SZ = (size_t)BB*NN*EE;   // 4,194,304 elements
    float*  Hb  = ws;                      // fp32 activations
    float*  Xb  = ws + SZ;                 // fp32 scratch (V fp32 / attn out / MLP mid)
    ushort* Qbf = (ushort*)(ws + 2*SZ);
    ushort* Kbf = Qbf + SZ;
    ushort* Vt  = Kbf + SZ;
    float*  BE  = ws + 2*SZ + (3*SZ)/2;

    base_even_k<<<BB, 256, 0, stream>>>(action_set, W_embed, b_embed, BE);
    embed_k<<<BB*NN, 256, 0, stream>>>(BE, ctx_act, ctx_rew, W_embed, b_embed, wpe, Hb);

    dim3 gg(BB*NN/64, EE/64);
    for (int l = 0; l < LL; ++l) {
        gemm_k<0,0,0,1><<<gg, 256, 0, stream>>>(Hb, Wq + (size_t)l*EE*EE, nullptr, nullptr, Qbf);
        gemm_k<0,0,0,1><<<gg, 256, 0, stream>>>(Hb, Wk + (size_t)l*EE*EE, nullptr, nullptr, Kbf);
        gemm_k<0,0,0,0><<<gg, 256, 0, stream>>>(Hb, Wv + (size_t)l*EE*EE, nullptr, nullptr, Xb);
        vtrans_k<<<dim3(256, 4), 256, 0, stream>>>(Xb, Vt);
        attn_k<<<256, 256, 0, stream>>>(Qbf, Kbf, Vt, Hb, Xb);
        ln_k<<<BB*NN, 256, 0, stream>>>(Xb, ln1g + l*EE, ln1b + l*EE, Hb);
        gemm_k<1,1,0,0><<<gg, 256, 0, stream>>>(Hb, W1 + (size_t)l*EE*EE, b1 + l*EE, nullptr, Xb);
        gemm_k<0,1,1,0><<<gg, 256, 0, stream>>>(Xb, W2 + (size_t)l*EE*EE, b2 + l*EE, Hb, Hb);
        ln_k<<<BB*NN, 256, 0, stream>>>(Hb, ln2g + l*EE, ln2b + l*EE, Hb);
    }
    pred_k<<<BB*TT, 256, 0, stream>>>(Hb, Wp, bp, out);
}

// Round 3
// 1140.131 us; speedup vs baseline: 3.0844x; 1.0492x over previous
//
#include <hip/hip_runtime.h>

// Transformer_67748814127473 — round 2: all-MFMA (bf16) + barrier-free j-split attention.
// B=8, T=1024, N=2048, E=256, L=4.

#define BB 8
#define TT 1024
#define NN 2048
#define EE 256
#define LL 4

typedef __attribute__((ext_vector_type(8))) short short8;
typedef __attribute__((ext_vector_type(4))) float f32x4;

__device__ inline ushort f2b(float f) {
    union { float f; unsigned u; } x; x.f = f;
    unsigned u = x.u;
    return (ushort)((u + 0x7fffu + ((u >> 16) & 1u)) >> 16);
}

// ---------------- weight prep: transpose + cast to bf16 ----------------
// 20 matrices (4 layers x {Wq,Wk,Wv,W1,W2}), each 256x256 fp32 [k][n] -> bf16 [n][k].
__global__ __launch_bounds__(256) void wprep_k(
    const float* __restrict__ Wq, const float* __restrict__ Wk,
    const float* __restrict__ Wv, const float* __restrict__ W1,
    const float* __restrict__ W2,
    ushort* __restrict__ WQKt, ushort* __restrict__ WVt,
    ushort* __restrict__ W1t, ushort* __restrict__ W2t)
{
    int id = blockIdx.x;          // 320 = 20 matrices x 16 tiles
    int m = id >> 4, t = id & 15;
    int l = m / 5, which = m % 5;
    const float* src; ushort* dst;
    size_t o = (size_t)l * 65536;
    switch (which) {
        case 0: src = Wq + o; dst = WQKt + (size_t)l*512*256;          break;
        case 1: src = Wk + o; dst = WQKt + (size_t)l*512*256 + 65536;  break;
        case 2: src = Wv + o; dst = WVt + o; break;
        case 3: src = W1 + o; dst = W1t + o; break;
        default: src = W2 + o; dst = W2t + o; break;
    }
    int tk = (t >> 2) * 64;   // src row block (k)
    int tn = (t & 3) * 64;    // src col block (n)
    __shared__ ushort T[64][68];
    int tid = threadIdx.x;
    int r = tid >> 4, c4 = (tid & 15) * 4;
    #pragma unroll
    for (int it = 0; it < 4; ++it) {
        int k = r + it*16;
        float4 v = *(const float4*)&src[(size_t)(tk + k)*256 + tn + c4];
        T[k][c4+0] = f2b(v.x); T[k][c4+1] = f2b(v.y);
        T[k][c4+2] = f2b(v.z); T[k][c4+3] = f2b(v.w);
    }
    __syncthreads();
    #pragma unroll
    for (int it = 0; it < 4; ++it) {
        int n = r + it*16;
        ushort4 ov;
        ov.x = T[c4+0][n]; ov.y = T[c4+1][n]; ov.z = T[c4+2][n]; ov.w = T[c4+3][n];
        *(ushort4*)&dst[(size_t)(tn + n)*256 + tk + c4] = ov;
    }
}

// ---------------- per-batch even-row base vector ----------------
__global__ __launch_bounds__(256) void base_even_k(
    const float* __restrict__ aset, const float* __restrict__ We,
    const float* __restrict__ be, float* __restrict__ BE)
{
    int b = blockIdx.x; int e = threadIdx.x;
    __shared__ float as[640];
    for (int i = e; i < 640; i += 256) as[i] = aset[b*640 + i];
    __syncthreads();
    float s = We[651*EE + e] + be[e];
    for (int f = 0; f < 640; ++f) s = fmaf(as[f], We[f*EE + e], s);
    BE[b*EE + e] = s;
}

// ---------------- embedding (8 rows per block), dual fp32+bf16 out ----------
__global__ __launch_bounds__(256) void embed_k(
    const float* __restrict__ BE, const float* __restrict__ ca,
    const float* __restrict__ cr, const float* __restrict__ We,
    const float* __restrict__ be, const float* __restrict__ wpe,
    float* __restrict__ H, ushort* __restrict__ Hbf)
{
    int e = threadIdx.x;
    #pragma unroll
    for (int k = 0; k < 8; ++k) {
        int rb = blockIdx.x * 8 + k;
        int b = rb >> 11, n = rb & (NN-1);
        float h;
        if ((n & 1) == 0) {
            h = BE[b*EE + e];
        } else {
            int t = n >> 1;
            h = We[651*EE + e] + be[e];
            const float* cap = ca + (size_t)(b*TT + t)*10;
            #pragma unroll
            for (int i = 0; i < 10; ++i) h = fmaf(cap[i], We[(640+i)*EE + e], h);
            h = fmaf(cr[b*TT + t], We[650*EE + e], h);
        }
        h = fmaf((float)(n + 1), We[652*EE + e], h);
        h += wpe[(size_t)n*EE + e];
        H[(size_t)rb*EE + e] = h;
        Hbf[(size_t)rb*EE + e] = f2b(h);
    }
}

// ---------------- bf16 MFMA GEMM: C = act(A @ Bw^T + bias) + Res ------------
// A: [M][256] bf16 rows. Bw: [N][256] bf16 rows (pre-transposed weights).
// OUT: 0 = fp32 to Cv[row*ldc+col]; 1 = bf16 to Cv[row*ldc+col];
//      2 = bf16 transposed V-layout: row=e, col=token -> Vt[(b*256+e)*2048+n].
template<int RELU, int BIAS, int RES, int OUT>
__global__ __launch_bounds__(256) void bgemm_k(
    const ushort* __restrict__ A, const ushort* __restrict__ Bw,
    const float* __restrict__ bias, const float* __restrict__ Res,
    void* __restrict__ Cv, int ldc)
{
    int tid = threadIdx.x;
    int w = tid >> 6, l = tid & 63;
    int lr = l & 15, lg = l >> 4;
    int rw = w >> 1, cw = w & 1;
    int row0 = blockIdx.x * 64 + rw*32;
    int col0 = blockIdx.y * 64 + cw*32;
    const ushort* Ap = A  + (size_t)(row0 + lr)*256 + lg*8;
    const ushort* Bp = Bw + (size_t)(col0 + lr)*256 + lg*8;
    f32x4 acc[2][2];
    #pragma unroll
    for (int i = 0; i < 2; ++i)
        #pragma unroll
        for (int j = 0; j < 2; ++j) acc[i][j] = (f32x4){0.f,0.f,0.f,0.f};
    #pragma unroll
    for (int kc = 0; kc < 8; ++kc) {
        short8 a0 = *(const short8*)(Ap + kc*32);
        short8 a1 = *(const short8*)(Ap + 16*256 + kc*32);
        short8 b0 = *(const short8*)(Bp + kc*32);
        short8 b1 = *(const short8*)(Bp + 16*256 + kc*32);
        acc[0][0] = __builtin_amdgcn_mfma_f32_16x16x32_bf16(a0, b0, acc[0][0], 0,0,0);
        acc[0][1] = __builtin_amdgcn_mfma_f32_16x16x32_bf16(a0, b1, acc[0][1], 0,0,0);
        acc[1][0] = __builtin_amdgcn_mfma_f32_16x16x32_bf16(a1, b0, acc[1][0], 0,0,0);
        acc[1][1] = __builtin_amdgcn_mfma_f32_16x16x32_bf16(a1, b1, acc[1][1], 0,0,0);
    }
    #pragma unroll
    for (int ri = 0; ri < 2; ++ri)
        #pragma unroll
        for (int ci = 0; ci < 2; ++ci)
            #pragma unroll
            for (int r = 0; r < 4; ++r) {
                int row = row0 + ri*16 + lg*4 + r;
                int col = col0 + ci*16 + lr;
                float x = acc[ri][ci][r];
                if (BIAS) x += bias[col];
                if (RELU) x = fmaxf(x, 0.f);
                if (RES)  x += Res[(size_t)row*256 + col];
                if (OUT == 0)      ((float*)Cv)[(size_t)row*ldc + col] = x;
                else if (OUT == 1) ((ushort*)Cv)[(size_t)row*ldc + col] = f2b(x);
                else {
                    int bb = col >> 11, n = col & (NN-1);
                    ((ushort*)Cv)[((size_t)(bb*256 + row))*NN + n] = f2b(x);
                }
            }
}

// ---------------- barrier-free j-split causal relu-attention ----------------
// X[b,i,:] = H[b,i,:] + (1/(i+1)) * sum_{j<=i} relu(q_i.k_j) * v_j
// Block (512 thr, 8 waves): tile pair (p, 63-p), waves = 4 j-slots x 2 row-halves.
// Adaptive slot allocation kA minimizes the max per-wave j-tile count (~17-22).
// Each wave: private S round-trip in its own LDS chunk (no in-loop barriers).
__global__ __launch_bounds__(512, 2) void attn_k(
    const ushort* __restrict__ QK, const ushort* __restrict__ Vt,
    const float* __restrict__ H, float* __restrict__ X)
{
    int blk = blockIdx.x;            // 256 = p(32) x b(8)
    int p = blk >> 3, b = blk & 7;
    int tid = threadIdx.x;
    int w = tid >> 6, l = tid & 63;
    int lr = l & 15, lg = l >> 4;
    int s = w >> 1, rh = w & 1;

    int NA = p + 1, NB = 64 - p;
    int kA = 1, best = 1 << 30;
    #pragma unroll
    for (int k = 1; k <= 3; ++k) {
        int wa = (NA + k - 1) / k;
        int kb = 4 - k;
        int wb = (NB + kb - 1) / kb;
        int mx = wa > wb ? wa : wb;
        if (mx < best) { best = mx; kA = k; }
    }
    bool tA = (s < kA);
    int z     = tA ? p : 63 - p;
    int NJ    = tA ? NA : NB;
    int part  = tA ? s : s - kA;
    int parts = tA ? kA : 4 - kA;
    int j0 = (part * NJ) / parts;
    int j1 = ((part + 1) * NJ) / parts;
    int row0 = z*32 + rh*16;

    __shared__ ushort Sl[8][512];      // 8 KB: per-wave private S (16x32 bf16, swizzled)
    __shared__ float comb[4][2048];    // 32 KB: O-combine, half (8 e-tiles) at a time
    char* Sb = (char*)&Sl[w][0];

    const ushort* Qp    = QK + ((size_t)(b*NN + row0 + lr))*512 + lg*8;
    const ushort* Kbase = QK + 256 + (size_t)b*NN*512 + lg*8;
    const ushort* Vbase = Vt + (size_t)b*EE*NN + lg*8;

    short8 qa[8];
    #pragma unroll
    for (int kc = 0; kc < 8; ++kc) qa[kc] = *(const short8*)(Qp + kc*32);

    f32x4 oacc[16];
    #pragma unroll
    for (int et = 0; et < 16; ++et) oacc[et] = (f32x4){0.f,0.f,0.f,0.f};

    for (int jt = j0; jt < j1; ++jt) {
        // QK^T: S[16 rows][32 cols] for this wave
        f32x4 s0 = {0.f,0.f,0.f,0.f}, s1 = {0.f,0.f,0.f,0.f};
        const ushort* Kp = Kbase + (size_t)(jt*32 + lr)*512;
        #pragma unroll
        for (int kc = 0; kc < 8; ++kc) {
            short8 k0 = *(const short8*)(Kp + kc*32);
            short8 k1 = *(const short8*)(Kp + 16*512 + kc*32);
            s0 = __builtin_amdgcn_mfma_f32_16x16x32_bf16(qa[kc], k0, s0, 0,0,0);
            s1 = __builtin_amdgcn_mfma_f32_16x16x32_bf16(qa[kc], k1, s1, 0,0,0);
        }
        // relu + causal mask + swizzled bf16 store (private; no barrier)
        #pragma unroll
        for (int r = 0; r < 4; ++r) {
            int i16 = lg*4 + r;
            int ig  = row0 + i16;
            int jg0 = jt*32 + lr;
            int jg1 = jg0 + 16;
            float v0 = s0[r] > 0.f ? s0[r] : 0.f;
            float v1 = s1[r] > 0.f ? s1[r] : 0.f;
            if (jg0 > ig) v0 = 0.f;
            if (jg1 > ig) v1 = 0.f;
            *(ushort*)(Sb + i16*64 + ((lr*2)        ^ ((i16 & 3) << 4))) = f2b(v0);
            *(ushort*)(Sb + i16*64 + (((16+lr)*2)   ^ ((i16 & 3) << 4))) = f2b(v1);
        }
        short8 sa = *(const short8*)(Sb + lr*64 + ((lg*16) ^ ((lr & 3) << 4)));
        // PV: O[16][256] += S @ V_jt
        const ushort* Vp = Vbase + (size_t)lr*NN + jt*32;
        #pragma unroll
        for (int et = 0; et < 16; ++et) {
            short8 vb = *(const short8*)(Vp + (size_t)(et*16)*NN);
            oacc[et] = __builtin_amdgcn_mfma_f32_16x16x32_bf16(sa, vb, oacc[et], 0,0,0);
        }
    }

    // ---- combine j-partials via LDS (two halves of 8 e-tiles), epilogue ----
    int gid = (tA ? 0 : 2) + rh;
    for (int h = 0; h < 2; ++h) {
        float* cb = &comb[gid][0];
        for (int r = 0; r < 3; ++r) {
            if (part == r) {
                #pragma unroll
                for (int et = 0; et < 8; ++et)
                    #pragma unroll
                    for (int q = 0; q < 4; ++q) {
                        int idx = et*256 + (lg*4+q)*16 + lr;
                        float v = oacc[h*8 + et][q];
                        if (r == 0) cb[idx] = v; else cb[idx] += v;
                    }
            }
            __syncthreads();
        }
        if (part == 0) {
            #pragma unroll
            for (int et = 0; et < 8; ++et)
                #pragma unroll
                for (int q = 0; q < 4; ++q) {
                    int ig = row0 + lg*4 + q;
                    float sc = 1.0f / (float)(ig + 1);
                    size_t base = ((size_t)(b*NN + ig))*EE + (h*8 + et)*16 + lr;
                    X[base] = H[base] + cb[et*256 + (lg*4+q)*16 + lr] * sc;
                }
        }
        __syncthreads();
    }
}

// ---------------- LayerNorm: 1 wave per row, dual fp32+bf16 out ----------------
__global__ __launch_bounds__(256) void ln_k(
    const float* __restrict__ Xin, const float* __restrict__ g,
    const float* __restrict__ bta, float* __restrict__ HoutF,
    ushort* __restrict__ HoutB)
{
    int w = threadIdx.x >> 6, l = threadIdx.x & 63;
    size_t row = (size_t)blockIdx.x*4 + w;
    float4 x = *(const float4*)&Xin[row*EE + l*4];
    float s  = x.x + x.y + x.z + x.w;
    float s2 = x.x*x.x + x.y*x.y + x.z*x.z + x.w*x.w;
    #pragma unroll
    for (int off = 1; off < 64; off <<= 1) {
        s  += __shfl_xor(s,  off);
        s2 += __shfl_xor(s2, off);
    }
    float mean = s * (1.0f/256.0f);
    float var  = s2 * (1.0f/256.0f) - mean*mean;
    float inv  = 1.0f / sqrtf(var + 1e-5f);
    float4 gv = *(const float4*)&g[l*4];
    float4 bv = *(const float4*)&bta[l*4];
    float4 y;
    y.x = (x.x - mean)*inv*gv.x + bv.x;
    y.y = (x.y - mean)*inv*gv.y + bv.y;
    y.z = (x.z - mean)*inv*gv.z + bv.z;
    y.w = (x.w - mean)*inv*gv.w + bv.w;
    *(float4*)&HoutF[row*EE + l*4] = y;
    ushort4 yb; yb.x = f2b(y.x); yb.y = f2b(y.y); yb.z = f2b(y.z); yb.w = f2b(y.w);
    *(ushort4*)&HoutB[row*EE + l*4] = yb;
}

// ---------------- prediction head (even rows only) ----------------
__global__ __launch_bounds__(256) void pred_k(
    const float* __restrict__ H, const float* __restrict__ Wp,
    const float* __restrict__ bp, float* __restrict__ out)
{
    int bt = blockIdx.x;
    int b = bt >> 10, t = bt & 1023;
    size_t row = (size_t)b*NN + 2*t;
    __shared__ float hs[256];
    __shared__ float pr[16][16];
    int tid = threadIdx.x;
    hs[tid] = H[row*EE + tid];
    __syncthreads();
    int c = tid & 15, seg = tid >> 4;
    float p = 0.f;
    if (c < 10) {
        #pragma unroll
        for (int e2 = 0; e2 < 16; ++e2)
            p = fmaf(hs[seg*16 + e2], Wp[(seg*16 + e2)*10 + c], p);
    }
    pr[seg][c] = p;
    __syncthreads();
    if (tid < 10) {
        float sacc = bp[tid];
        #pragma unroll
        for (int k2 = 0; k2 < 16; ++k2) sacc += pr[k2][tid];
        out[(size_t)bt*10 + tid] = sacc;
    }
}

extern "C" void kernel_launch(void* const* d_in, const int* in_sizes, int n_in,
                              void* d_out, int out_size, void* d_ws, size_t ws_size,
                              hipStream_t stream)
{
    const float* action_set = (const float*)d_in[1];
    const float* ctx_act    = (const float*)d_in[2];
    const float* ctx_rew    = (const float*)d_in[3];
    const float* W_embed    = (const float*)d_in[4];
    const float* b_embed    = (const float*)d_in[5];
    const float* wpe        = (const float*)d_in[6];
    const float* Wq         = (const float*)d_in[7];
    const float* Wk         = (const float*)d_in[8];
    const float* Wv         = (const float*)d_in[9];
    const float* ln1g       = (const float*)d_in[10];
    const float* ln1b       = (const float*)d_in[11];
    const float* W1         = (const float*)d_in[12];
    const float* b1         = (const float*)d_in[13];
    const float* W2         = (const float*)d_in[14];
    const float* b2         = (const float*)d_in[15];
    const float* ln2g       = (const float*)d_in[16];
    const float* ln2b       = (const float*)d_in[17];
    const float* Wp         = (const float*)d_in[18];
    const float* bp         = (const float*)d_in[19];
    float* out = (float*)d_out;

    float* ws = (float*)d_ws;
    const size_t SZ = (size_t)BB*NN*EE;   // 4,194,304
    size_t o = 0;
    float*  Hb   = ws;               o += SZ;        // fp32 residual stream
    float*  Xb   = ws + o;           o += SZ;        // fp32 scratch (attn out / ln1 out)
    ushort* Hbf  = (ushort*)(ws+o);  o += SZ/2;      // bf16 stream copy
    ushort* QKb  = (ushort*)(ws+o);  o += SZ;        // [16384][512] bf16; aliased as MLP-mid
    ushort* Vtb  = (ushort*)(ws+o);  o += SZ/2;      // [B][E][N] bf16; aliased as ln1-bf16
    ushort* WQKt = (ushort*)(ws+o);  o += 262144;    // 4 x [512][256]
    ushort* WVt  = (ushort*)(ws+o);  o += 131072;    // 4 x [256][256]
    ushort* W1t  = (ushort*)(ws+o);  o += 131072;
    ushort* W2t  = (ushort*)(ws+o);  o += 131072;
    float*  BE   = ws + o;

    wprep_k<<<320, 256, 0, stream>>>(Wq, Wk, Wv, W1, W2, WQKt, WVt, W1t, W2t);
    base_even_k<<<BB, 256, 0, stream>>>(action_set, W_embed, b_embed, BE);
    embed_k<<<BB*NN/8, 256, 0, stream>>>(BE, ctx_act, ctx_rew, W_embed, b_embed, wpe, Hb, Hbf);

    for (int l = 0; l < LL; ++l) {
        // fused Q|K GEMM -> QKb [16384][512]
        bgemm_k<0,0,0,1><<<dim3(256, 8), 256, 0, stream>>>(
            Hbf, WQKt + (size_t)l*512*256, nullptr, nullptr, QKb, 512);
        // V GEMM, output directly transposed -> Vtb [B][E][N]
        bgemm_k<0,0,0,2><<<dim3(4, 256), 256, 0, stream>>>(
            WVt + (size_t)l*65536, Hbf, nullptr, nullptr, Vtb, 0);
        attn_k<<<256, 512, 0, stream>>>(QKb, Vtb, Hb, Xb);
        // ln1: Xb -> Xb (fp32, in-place) + Vtb-region (bf16)
        ln_k<<<BB*NN/4, 256, 0, stream>>>(Xb, ln1g + l*EE, ln1b + l*EE, Xb, Vtb);
        // mlp1: relu(ln1 @ W1 + b1) -> QKb-region (bf16)
        bgemm_k<1,1,0,1><<<dim3(256, 4), 256, 0, stream>>>(
            Vtb, W1t + (size_t)l*65536, b1 + l*EE, nullptr, QKb, 256);
        // mlp2: mid @ W2 + b2 + ln1(fp32) -> Hb (fp32)
        bgemm_k<0,1,1,0><<<dim3(256, 4), 256, 0, stream>>>(
            QKb, W2t + (size_t)l*65536, b2 + l*EE, Xb, Hb, 256);
        // ln2: Hb -> Hb (in-place) + Hbf
        ln_k<<<BB*NN/4, 256, 0, stream>>>(Hb, ln2g + l*EE, ln2b + l*EE, Hb, Hbf);
    }
    pred_k<<<BB*TT, 256, 0, stream>>>(Hb, Wp, bp, out);
}

// Round 4
// 858.866 us; speedup vs baseline: 4.0944x; 1.3275x over previous
//
#include <hip/hip_runtime.h>

// Transformer_67748814127473 — round 3: register-only-S attention (swapped MFMA
// + cvt_pk/shfl repack), 64x64-per-wave bgemm. B=8, T=1024, N=2048, E=256, L=4.

#define BB 8
#define TT 1024
#define NN 2048
#define EE 256
#define LL 4

typedef __attribute__((ext_vector_type(8))) short short8;
typedef __attribute__((ext_vector_type(4))) float f32x4;

__device__ inline ushort f2b(float f) {
    union { float f; unsigned u; } x; x.f = f;
    unsigned u = x.u;
    return (ushort)((u + 0x7fffu + ((u >> 16) & 1u)) >> 16);
}
__device__ inline unsigned cvtpk(float lo, float hi) {
    unsigned r;
    asm volatile("v_cvt_pk_bf16_f32 %0, %1, %2" : "=v"(r) : "v"(lo), "v"(hi));
    return r;
}

// ---------------- weight prep: transpose + cast to bf16 ----------------
__global__ __launch_bounds__(256) void wprep_k(
    const float* __restrict__ Wq, const float* __restrict__ Wk,
    const float* __restrict__ Wv, const float* __restrict__ W1,
    const float* __restrict__ W2,
    ushort* __restrict__ WQKt, ushort* __restrict__ WVt,
    ushort* __restrict__ W1t, ushort* __restrict__ W2t)
{
    int id = blockIdx.x;          // 320 = 20 matrices x 16 tiles
    int m = id >> 4, t = id & 15;
    int l = m / 5, which = m % 5;
    const float* src; ushort* dst;
    size_t o = (size_t)l * 65536;
    switch (which) {
        case 0: src = Wq + o; dst = WQKt + (size_t)l*512*256;          break;
        case 1: src = Wk + o; dst = WQKt + (size_t)l*512*256 + 65536;  break;
        case 2: src = Wv + o; dst = WVt + o; break;
        case 3: src = W1 + o; dst = W1t + o; break;
        default: src = W2 + o; dst = W2t + o; break;
    }
    int tk = (t >> 2) * 64;
    int tn = (t & 3) * 64;
    __shared__ ushort T[64][68];
    int tid = threadIdx.x;
    int r = tid >> 4, c4 = (tid & 15) * 4;
    #pragma unroll
    for (int it = 0; it < 4; ++it) {
        int k = r + it*16;
        float4 v = *(const float4*)&src[(size_t)(tk + k)*256 + tn + c4];
        T[k][c4+0] = f2b(v.x); T[k][c4+1] = f2b(v.y);
        T[k][c4+2] = f2b(v.z); T[k][c4+3] = f2b(v.w);
    }
    __syncthreads();
    #pragma unroll
    for (int it = 0; it < 4; ++it) {
        int n = r + it*16;
        ushort4 ov;
        ov.x = T[c4+0][n]; ov.y = T[c4+1][n]; ov.z = T[c4+2][n]; ov.w = T[c4+3][n];
        *(ushort4*)&dst[(size_t)(tn + n)*256 + tk + c4] = ov;
    }
}

// ---------------- per-batch even-row base vector ----------------
__global__ __launch_bounds__(256) void base_even_k(
    const float* __restrict__ aset, const float* __restrict__ We,
    const float* __restrict__ be, float* __restrict__ BE)
{
    int b = blockIdx.x; int e = threadIdx.x;
    __shared__ float as[640];
    for (int i = e; i < 640; i += 256) as[i] = aset[b*640 + i];
    __syncthreads();
    float s = We[651*EE + e] + be[e];
    for (int f = 0; f < 640; ++f) s = fmaf(as[f], We[f*EE + e], s);
    BE[b*EE + e] = s;
}

// ---------------- embedding (8 rows per block), dual fp32+bf16 out ----------
__global__ __launch_bounds__(256) void embed_k(
    const float* __restrict__ BE, const float* __restrict__ ca,
    const float* __restrict__ cr, const float* __restrict__ We,
    const float* __restrict__ be, const float* __restrict__ wpe,
    float* __restrict__ H, ushort* __restrict__ Hbf)
{
    int e = threadIdx.x;
    #pragma unroll
    for (int k = 0; k < 8; ++k) {
        int rb = blockIdx.x * 8 + k;
        int b = rb >> 11, n = rb & (NN-1);
        float h;
        if ((n & 1) == 0) {
            h = BE[b*EE + e];
        } else {
            int t = n >> 1;
            h = We[651*EE + e] + be[e];
            const float* cap = ca + (size_t)(b*TT + t)*10;
            #pragma unroll
            for (int i = 0; i < 10; ++i) h = fmaf(cap[i], We[(640+i)*EE + e], h);
            h = fmaf(cr[b*TT + t], We[650*EE + e], h);
        }
        h = fmaf((float)(n + 1), We[652*EE + e], h);
        h += wpe[(size_t)n*EE + e];
        H[(size_t)rb*EE + e] = h;
        Hbf[(size_t)rb*EE + e] = f2b(h);
    }
}

// ---------------- bf16 MFMA GEMM, 64x64 per wave, 128x128 per block ---------
// A: [M][256] bf16. Bw: [N][256] bf16 (pre-transposed weights).
// OUT: 0 fp32; 1 bf16; 2 bf16 V-transposed (row=e, col=token).
template<int RELU, int BIAS, int RES, int OUT>
__global__ __launch_bounds__(256, 2) void bgemm_k(
    const ushort* __restrict__ A, const ushort* __restrict__ Bw,
    const float* __restrict__ bias, const float* __restrict__ Res,
    void* __restrict__ Cv, int ldc)
{
    int tid = threadIdx.x;
    int w = tid >> 6, l = tid & 63;
    int lr = l & 15, lg = l >> 4;
    int wr = w >> 1, wc = w & 1;
    int row0 = blockIdx.x * 128 + wr*64;
    int col0 = blockIdx.y * 128 + wc*64;
    const ushort* Ap = A  + (size_t)(row0 + lr)*256 + lg*8;
    const ushort* Bp = Bw + (size_t)(col0 + lr)*256 + lg*8;
    f32x4 acc[4][4];
    #pragma unroll
    for (int i = 0; i < 4; ++i)
        #pragma unroll
        for (int j = 0; j < 4; ++j) acc[i][j] = (f32x4){0.f,0.f,0.f,0.f};
    #pragma unroll
    for (int kc = 0; kc < 8; ++kc) {
        short8 af[4], bf[4];
        #pragma unroll
        for (int rg = 0; rg < 4; ++rg) af[rg] = *(const short8*)(Ap + (size_t)rg*16*256 + kc*32);
        #pragma unroll
        for (int cg = 0; cg < 4; ++cg) bf[cg] = *(const short8*)(Bp + (size_t)cg*16*256 + kc*32);
        #pragma unroll
        for (int rg = 0; rg < 4; ++rg)
            #pragma unroll
            for (int cg = 0; cg < 4; ++cg)
                acc[rg][cg] = __builtin_amdgcn_mfma_f32_16x16x32_bf16(af[rg], bf[cg], acc[rg][cg], 0,0,0);
    }
    #pragma unroll
    for (int rg = 0; rg < 4; ++rg)
        #pragma unroll
        for (int cg = 0; cg < 4; ++cg)
            #pragma unroll
            for (int r = 0; r < 4; ++r) {
                int row = row0 + rg*16 + lg*4 + r;
                int col = col0 + cg*16 + lr;
                float x = acc[rg][cg][r];
                if (BIAS) x += bias[col];
                if (RELU) x = fmaxf(x, 0.f);
                if (RES)  x += Res[(size_t)row*256 + col];
                if (OUT == 0)      ((float*)Cv)[(size_t)row*ldc + col] = x;
                else if (OUT == 1) ((ushort*)Cv)[(size_t)row*ldc + col] = f2b(x);
                else {
                    int bb = col >> 11, n = col & (NN-1);
                    ((ushort*)Cv)[((size_t)(bb*256 + row))*NN + n] = f2b(x);
                }
            }
}

// ---------------- register-only-S causal relu-attention ----------------
// X[b,i,:] = H[b,i,:] + (1/(i+1)) * sum_{j<=i} relu(q_i.k_j) * v_j
// 512 blocks = 64 slice-pairs (s,127-s) x 8 batches. 8 waves = 2 slices x 4
// j-quarters (slice chosen by (w&1)^((w>>2)&1) for SIMD load balance).
// S^T computed via mfma(K,Q); repack to PV A-frags with cvt_pk + 8 shfl.
// No LDS/barriers in the j-loop; 4-way O-combine in LDS at the end.
__global__ __launch_bounds__(512, 2) void attn_k(
    const ushort* __restrict__ QK, const ushort* __restrict__ Vt,
    const float* __restrict__ H, float* __restrict__ X)
{
    int blk = blockIdx.x;            // pk*8 + b, pk in 0..63
    int pk = blk >> 3, b = blk & 7;
    int tid = threadIdx.x;
    int w = tid >> 6, l = tid & 63;
    int lr = l & 15, lg = l >> 4;
    int sel  = (w & 1) ^ ((w >> 2) & 1);
    int part = w >> 1;
    int s  = sel ? (127 - pk) : pk;  // 16-row slice index within batch
    int i0 = s * 16;
    int NT = (s >> 1) + 1;           // causal j-tiles of 32
    int j0 = (part * NT) >> 2;
    int j1 = ((part + 1) * NT) >> 2;

    __shared__ float comb[2][5440];  // per-slice padded combine area

    const ushort* Qp    = QK + ((size_t)(b*NN + i0 + lr))*512 + lg*8;
    const ushort* Kbase = QK + 256 + (size_t)b*NN*512 + lg*8;
    const ushort* Vbase = Vt + (size_t)(b*EE + lr)*NN + lg*8;

    short8 qb[8];
    #pragma unroll
    for (int kc = 0; kc < 8; ++kc) qb[kc] = *(const short8*)(Qp + kc*32);

    f32x4 oacc[16];
    #pragma unroll
    for (int et = 0; et < 16; ++et) oacc[et] = (f32x4){0.f,0.f,0.f,0.f};

    int ig = i0 + lr;
    for (int jt = j0; jt < j1; ++jt) {
        // issue all loads up front: K (32 rows) then V (16 e-tiles)
        const ushort* Kp = Kbase + (size_t)(jt*32 + lr)*512;
        short8 ka0[8], ka1[8];
        #pragma unroll
        for (int kc = 0; kc < 8; ++kc) {
            ka0[kc] = *(const short8*)(Kp + kc*32);
            ka1[kc] = *(const short8*)(Kp + (size_t)16*512 + kc*32);
        }
        const ushort* Vp = Vbase + jt*32;
        short8 vf[16];
        #pragma unroll
        for (int et = 0; et < 16; ++et)
            vf[et] = *(const short8*)(Vp + (size_t)et*16*NN);
        // QK^T (swapped): c0/c1 hold S^T[j][i], j = jt*32 + 4lg + r (+16)
        f32x4 c0 = {0.f,0.f,0.f,0.f}, c1 = {0.f,0.f,0.f,0.f};
        #pragma unroll
        for (int kc = 0; kc < 8; ++kc) {
            c0 = __builtin_amdgcn_mfma_f32_16x16x32_bf16(ka0[kc], qb[kc], c0, 0,0,0);
            c1 = __builtin_amdgcn_mfma_f32_16x16x32_bf16(ka1[kc], qb[kc], c1, 0,0,0);
        }
        // relu + causal mask (j <= i)
        #pragma unroll
        for (int r = 0; r < 4; ++r) {
            int jg = jt*32 + lg*4 + r;
            c0[r] = (jg <= ig) ? fmaxf(c0[r], 0.f) : 0.f;
            c1[r] = (jg + 16 <= ig) ? fmaxf(c1[r], 0.f) : 0.f;
        }
        // pack to bf16 pairs and repack C-layout -> PV A-frag via shfl
        unsigned u0 = cvtpk(c0[0], c0[1]), u1 = cvtpk(c0[2], c0[3]);
        unsigned u2 = cvtpk(c1[0], c1[1]), u3 = cvtpk(c1[2], c1[3]);
        int srcA = 32*(lg & 1) + lr;
        int srcB = srcA + 16;
        unsigned a0A = __shfl((int)u0, srcA), a1A = __shfl((int)u1, srcA);
        unsigned a0B = __shfl((int)u0, srcB), a1B = __shfl((int)u1, srcB);
        unsigned b0A = __shfl((int)u2, srcA), b1A = __shfl((int)u3, srcA);
        unsigned b0B = __shfl((int)u2, srcB), b1B = __shfl((int)u3, srcB);
        bool lo = (lg < 2);
        union { unsigned u[4]; short8 v; } sv;
        sv.u[0] = lo ? a0A : b0A;
        sv.u[1] = lo ? a1A : b1A;
        sv.u[2] = lo ? a0B : b0B;
        sv.u[3] = lo ? a1B : b1B;
        short8 sa = sv.v;
        // PV: O[16][256] += S @ V_jt
        #pragma unroll
        for (int et = 0; et < 16; ++et)
            oacc[et] = __builtin_amdgcn_mfma_f32_16x16x32_bf16(sa, vf[et], oacc[et], 0,0,0);
    }

    // ---- 4-way combine (parts 1..3 -> LDS) + epilogue by part 0 ----
    float* cb = &comb[sel][0];
    #pragma unroll
    for (int rnd = 1; rnd <= 3; ++rnd) {
        if (part == rnd) {
            #pragma unroll
            for (int et = 0; et < 16; ++et)
                #pragma unroll
                for (int r = 0; r < 4; ++r) {
                    int idx = et*340 + l*5 + r;
                    float v = oacc[et][r];
                    if (rnd == 1) cb[idx] = v; else cb[idx] += v;
                }
        }
        __syncthreads();
    }
    if (part == 0) {
        #pragma unroll
        for (int et = 0; et < 16; ++et)
            #pragma unroll
            for (int r = 0; r < 4; ++r) {
                int irow = i0 + lg*4 + r;
                float o = oacc[et][r] + cb[et*340 + l*5 + r];
                float sc = 1.0f / (float)(irow + 1);
                size_t base = ((size_t)(b*NN + irow))*EE + et*16 + lr;
                X[base] = H[base] + o * sc;
            }
    }
}

// ---------------- LayerNorm: 1 wave per row, dual fp32+bf16 out --------------
__global__ __launch_bounds__(256) void ln_k(
    const float* __restrict__ Xin, const float* __restrict__ g,
    const float* __restrict__ bta, float* __restrict__ HoutF,
    ushort* __restrict__ HoutB)
{
    int w = threadIdx.x >> 6, l = threadIdx.x & 63;
    size_t row = (size_t)blockIdx.x*4 + w;
    float4 x = *(const float4*)&Xin[row*EE + l*4];
    float s  = x.x + x.y + x.z + x.w;
    float s2 = x.x*x.x + x.y*x.y + x.z*x.z + x.w*x.w;
    #pragma unroll
    for (int off = 1; off < 64; off <<= 1) {
        s  += __shfl_xor(s,  off);
        s2 += __shfl_xor(s2, off);
    }
    float mean = s * (1.0f/256.0f);
    float var  = s2 * (1.0f/256.0f) - mean*mean;
    float inv  = 1.0f / sqrtf(var + 1e-5f);
    float4 gv = *(const float4*)&g[l*4];
    float4 bv = *(const float4*)&bta[l*4];
    float4 y;
    y.x = (x.x - mean)*inv*gv.x + bv.x;
    y.y = (x.y - mean)*inv*gv.y + bv.y;
    y.z = (x.z - mean)*inv*gv.z + bv.z;
    y.w = (x.w - mean)*inv*gv.w + bv.w;
    *(float4*)&HoutF[row*EE + l*4] = y;
    ushort4 yb; yb.x = f2b(y.x); yb.y = f2b(y.y); yb.z = f2b(y.z); yb.w = f2b(y.w);
    *(ushort4*)&HoutB[row*EE + l*4] = yb;
}

// ---------------- prediction head (even rows only) ----------------
__global__ __launch_bounds__(256) void pred_k(
    const float* __restrict__ H, const float* __restrict__ Wp,
    const float* __restrict__ bp, float* __restrict__ out)
{
    int bt = blockIdx.x;
    int b = bt >> 10, t = bt & 1023;
    size_t row = (size_t)b*NN + 2*t;
    __shared__ float hs[256];
    __shared__ float pr[16][16];
    int tid = threadIdx.x;
    hs[tid] = H[row*EE + tid];
    __syncthreads();
    int c = tid & 15, seg = tid >> 4;
    float p = 0.f;
    if (c < 10) {
        #pragma unroll
        for (int e2 = 0; e2 < 16; ++e2)
            p = fmaf(hs[seg*16 + e2], Wp[(seg*16 + e2)*10 + c], p);
    }
    pr[seg][c] = p;
    __syncthreads();
    if (tid < 10) {
        float sacc = bp[tid];
        #pragma unroll
        for (int k2 = 0; k2 < 16; ++k2) sacc += pr[k2][tid];
        out[(size_t)bt*10 + tid] = sacc;
    }
}

extern "C" void kernel_launch(void* const* d_in, const int* in_sizes, int n_in,
                              void* d_out, int out_size, void* d_ws, size_t ws_size,
                              hipStream_t stream)
{
    const float* action_set = (const float*)d_in[1];
    const float* ctx_act    = (const float*)d_in[2];
    const float* ctx_rew    = (const float*)d_in[3];
    const float* W_embed    = (const float*)d_in[4];
    const float* b_embed    = (const float*)d_in[5];
    const float* wpe        = (const float*)d_in[6];
    const float* Wq         = (const float*)d_in[7];
    const float* Wk         = (const float*)d_in[8];
    const float* Wv         = (const float*)d_in[9];
    const float* ln1g       = (const float*)d_in[10];
    const float* ln1b       = (const float*)d_in[11];
    const float* W1         = (const float*)d_in[12];
    const float* b1         = (const float*)d_in[13];
    const float* W2         = (const float*)d_in[14];
    const float* b2         = (const float*)d_in[15];
    const float* ln2g       = (const float*)d_in[16];
    const float* ln2b       = (const float*)d_in[17];
    const float* Wp         = (const float*)d_in[18];
    const float* bp         = (const float*)d_in[19];
    float* out = (float*)d_out;

    float* ws = (float*)d_ws;
    const size_t SZ = (size_t)BB*NN*EE;   // 4,194,304
    size_t o = 0;
    float*  Hb   = ws;               o += SZ;        // fp32 residual stream
    float*  Xb   = ws + o;           o += SZ;        // fp32 scratch
    ushort* Hbf  = (ushort*)(ws+o);  o += SZ/2;      // bf16 stream copy
    ushort* QKb  = (ushort*)(ws+o);  o += SZ;        // [16384][512] bf16; MLP-mid alias
    ushort* Vtb  = (ushort*)(ws+o);  o += SZ/2;      // [B][E][N] bf16; ln1-bf16 alias
    ushort* WQKt = (ushort*)(ws+o);  o += 262144;
    ushort* WVt  = (ushort*)(ws+o);  o += 131072;
    ushort* W1t  = (ushort*)(ws+o);  o += 131072;
    ushort* W2t  = (ushort*)(ws+o);  o += 131072;
    float*  BE   = ws + o;

    wprep_k<<<320, 256, 0, stream>>>(Wq, Wk, Wv, W1, W2, WQKt, WVt, W1t, W2t);
    base_even_k<<<BB, 256, 0, stream>>>(action_set, W_embed, b_embed, BE);
    embed_k<<<BB*NN/8, 256, 0, stream>>>(BE, ctx_act, ctx_rew, W_embed, b_embed, wpe, Hb, Hbf);

    for (int l = 0; l < LL; ++l) {
        // fused Q|K GEMM -> QKb [16384][512]
        bgemm_k<0,0,0,1><<<dim3(128, 4), 256, 0, stream>>>(
            Hbf, WQKt + (size_t)l*512*256, nullptr, nullptr, QKb, 512);
        // V GEMM, output directly transposed -> Vtb [B][E][N]
        bgemm_k<0,0,0,2><<<dim3(2, 128), 256, 0, stream>>>(
            WVt + (size_t)l*65536, Hbf, nullptr, nullptr, Vtb, 0);
        attn_k<<<512, 512, 0, stream>>>(QKb, Vtb, Hb, Xb);
        // ln1: Xb -> Xb (fp32, in-place) + Vtb-region (bf16)
        ln_k<<<BB*NN/4, 256, 0, stream>>>(Xb, ln1g + l*EE, ln1b + l*EE, Xb, Vtb);
        // mlp1: relu(ln1 @ W1 + b1) -> QKb-region (bf16)
        bgemm_k<1,1,0,1><<<dim3(128, 2), 256, 0, stream>>>(
            Vtb, W1t + (size_t)l*65536, b1 + l*EE, nullptr, QKb, 256);
        // mlp2: mid @ W2 + b2 + ln1(fp32) -> Hb (fp32)
        bgemm_k<0,1,1,0><<<dim3(128, 2), 256, 0, stream>>>(
            QKb, W2t + (size_t)l*65536, b2 + l*EE, Xb, Hb, 256);
        // ln2: Hb -> Hb (in-place) + Hbf
        ln_k<<<BB*NN/4, 256, 0, stream>>>(Hb, ln2g + l*EE, ln2b + l*EE, Hb, Hbf);
    }
    pred_k<<<BB*TT, 256, 0, stream>>>(Hb, Wp, bp, out);
}

// Round 5
// 540.265 us; speedup vs baseline: 6.5090x; 1.5897x over previous
//
#include <hip/hip_runtime.h>

// Transformer_67748814127473 — round 4: fragment-linear packed operands.
// Every MFMA A/B fragment load is one contiguous 1KB wave-load.
// B=8, T=1024, N=2048, E=256, L=4.

#define BB 8
#define TT 1024
#define NN 2048
#define EE 256
#define LL 4

typedef __attribute__((ext_vector_type(8))) short short8;
typedef __attribute__((ext_vector_type(4))) float f32x4;

__device__ inline ushort f2b(float f) {
    union { float f; unsigned u; } x; x.f = f;
    unsigned u = x.u;
    return (ushort)((u + 0x7fffu + ((u >> 16) & 1u)) >> 16);
}
__device__ inline unsigned cvtpk(float lo, float hi) {
    unsigned r;
    asm volatile("v_cvt_pk_bf16_f32 %0, %1, %2" : "=v"(r) : "v"(lo), "v"(hi));
    return r;
}
// fragment-linear pack for K=256 operands: tile16(row) x kchunk32 -> [lane][8]
__device__ inline size_t pk256(int row, int k) {
    return ((size_t)((row >> 4) * 8 + (k >> 5))) * 512
         + (size_t)((((k >> 3) & 3) * 16 + (row & 15)) * 8 + (k & 7));
}

// ---------------- weight prep: transpose + cast + frag-pack ----------------
__global__ __launch_bounds__(256) void wprep_k(
    const float* __restrict__ Wq, const float* __restrict__ Wk,
    const float* __restrict__ Wv, const float* __restrict__ W1,
    const float* __restrict__ W2,
    ushort* __restrict__ WQKt, ushort* __restrict__ WVt,
    ushort* __restrict__ W1t, ushort* __restrict__ W2t)
{
    int id = blockIdx.x;          // 320 = 20 matrices x 16 tiles
    int m = id >> 4, t = id & 15;
    int l = m / 5, which = m % 5;
    const float* src; ushort* dst;
    size_t o = (size_t)l * 65536;
    switch (which) {
        case 0: src = Wq + o; dst = WQKt + (size_t)l*131072;          break;
        case 1: src = Wk + o; dst = WQKt + (size_t)l*131072 + 65536;  break;
        case 2: src = Wv + o; dst = WVt + o; break;
        case 3: src = W1 + o; dst = W1t + o; break;
        default: src = W2 + o; dst = W2t + o; break;
    }
    int tk = (t >> 2) * 64;   // k block
    int tn = (t & 3) * 64;    // n block (output col)
    __shared__ ushort T[64][68];
    int tid = threadIdx.x;
    int r = tid >> 4, c4 = (tid & 15) * 4;
    #pragma unroll
    for (int it = 0; it < 4; ++it) {
        int k = r + it*16;
        float4 v = *(const float4*)&src[(size_t)(tk + k)*256 + tn + c4];
        T[k][c4+0] = f2b(v.x); T[k][c4+1] = f2b(v.y);
        T[k][c4+2] = f2b(v.z); T[k][c4+3] = f2b(v.w);
    }
    __syncthreads();
    #pragma unroll
    for (int it = 0; it < 4; ++it) {
        int n = tn + r + it*16;
        int k0 = tk + c4;
        ushort4 ov;
        ov.x = T[c4+0][n-tn]; ov.y = T[c4+1][n-tn];
        ov.z = T[c4+2][n-tn]; ov.w = T[c4+3][n-tn];
        *(ushort4*)&dst[pk256(n, k0)] = ov;
    }
}

// ---------------- per-batch even-row base vector ----------------
__global__ __launch_bounds__(256) void base_even_k(
    const float* __restrict__ aset, const float* __restrict__ We,
    const float* __restrict__ be, float* __restrict__ BE)
{
    int b = blockIdx.x; int e = threadIdx.x;
    __shared__ float as[640];
    for (int i = e; i < 640; i += 256) as[i] = aset[b*640 + i];
    __syncthreads();
    float s = We[651*EE + e] + be[e];
    for (int f = 0; f < 640; ++f) s = fmaf(as[f], We[f*EE + e], s);
    BE[b*EE + e] = s;
}

// ---------------- embedding (8 rows per block), fp32 + packed bf16 ----------
__global__ __launch_bounds__(256) void embed_k(
    const float* __restrict__ BE, const float* __restrict__ ca,
    const float* __restrict__ cr, const float* __restrict__ We,
    const float* __restrict__ be, const float* __restrict__ wpe,
    float* __restrict__ H, ushort* __restrict__ Hbf)
{
    int e = threadIdx.x;
    #pragma unroll
    for (int k = 0; k < 8; ++k) {
        int rb = blockIdx.x * 8 + k;
        int b = rb >> 11, n = rb & (NN-1);
        float h;
        if ((n & 1) == 0) {
            h = BE[b*EE + e];
        } else {
            int t = n >> 1;
            h = We[651*EE + e] + be[e];
            const float* cap = ca + (size_t)(b*TT + t)*10;
            #pragma unroll
            for (int i = 0; i < 10; ++i) h = fmaf(cap[i], We[(640+i)*EE + e], h);
            h = fmaf(cr[b*TT + t], We[650*EE + e], h);
        }
        h = fmaf((float)(n + 1), We[652*EE + e], h);
        h += wpe[(size_t)n*EE + e];
        H[(size_t)rb*EE + e] = h;
        Hbf[pk256(rb, e)] = f2b(h);
    }
}

// ---------------- bf16 MFMA GEMM, 64x64 per wave, 128x128 per block ---------
// A, Bw: fragment-packed bf16 (pk256 layout).
// OUT: 0 fp32 linear; 1 bf16 packed (pk256); 2 V-pack (row=e,col=token);
//      3 QK split pack (col<256 -> Cv, else Cv2 with k=col-256).
template<int RELU, int BIAS, int RES, int OUT>
__global__ __launch_bounds__(256, 2) void bgemm_k(
    const ushort* __restrict__ A, const ushort* __restrict__ Bw,
    const float* __restrict__ bias, const float* __restrict__ Res,
    void* __restrict__ Cv, void* __restrict__ Cv2, int ldc)
{
    int tid = threadIdx.x;
    int w = tid >> 6, l = tid & 63;
    int lr = l & 15, lg = l >> 4;
    int wr = w >> 1, wc = w & 1;
    int rt0 = blockIdx.x * 8 + wr*4;    // row tile (16-row units)
    int ct0 = blockIdx.y * 8 + wc*4;    // col tile
    const ushort* Ap = A  + (size_t)rt0*4096 + l*8;
    const ushort* Bp = Bw + (size_t)ct0*4096 + l*8;
    f32x4 acc[4][4];
    #pragma unroll
    for (int i = 0; i < 4; ++i)
        #pragma unroll
        for (int j = 0; j < 4; ++j) acc[i][j] = (f32x4){0.f,0.f,0.f,0.f};
    #pragma unroll
    for (int kc = 0; kc < 8; ++kc) {
        short8 af[4], bf[4];
        #pragma unroll
        for (int rg = 0; rg < 4; ++rg) af[rg] = *(const short8*)(Ap + (size_t)rg*4096 + kc*512);
        #pragma unroll
        for (int cg = 0; cg < 4; ++cg) bf[cg] = *(const short8*)(Bp + (size_t)cg*4096 + kc*512);
        #pragma unroll
        for (int rg = 0; rg < 4; ++rg)
            #pragma unroll
            for (int cg = 0; cg < 4; ++cg)
                acc[rg][cg] = __builtin_amdgcn_mfma_f32_16x16x32_bf16(af[rg], bf[cg], acc[rg][cg], 0,0,0);
    }
    #pragma unroll
    for (int rg = 0; rg < 4; ++rg)
        #pragma unroll
        for (int cg = 0; cg < 4; ++cg)
            #pragma unroll
            for (int r = 0; r < 4; ++r) {
                int row = rt0*16 + rg*16 + lg*4 + r;
                int col = ct0*16 + cg*16 + lr;
                float x = acc[rg][cg][r];
                if (BIAS) x += bias[col];
                if (RELU) x = fmaxf(x, 0.f);
                if (RES)  x += Res[(size_t)row*256 + col];
                if (OUT == 0)      ((float*)Cv)[(size_t)row*ldc + col] = x;
                else if (OUT == 1) ((ushort*)Cv)[pk256(row, col)] = f2b(x);
                else if (OUT == 2) {
                    int bb = col >> 11, n = col & (NN-1);
                    size_t idx = ((size_t)(bb*64 + (n >> 5)) * 16 + (row >> 4)) * 512
                               + (size_t)((((n >> 3) & 3) * 16 + (row & 15)) * 8 + (n & 7));
                    ((ushort*)Cv)[idx] = f2b(x);
                } else {
                    if (col < 256) ((ushort*)Cv)[pk256(row, col)]        = f2b(x);
                    else           ((ushort*)Cv2)[pk256(row, col - 256)] = f2b(x);
                }
            }
}

// ---------------- register-only-S causal relu-attention (packed operands) ----
// X[b,i,:] = H[b,i,:] + (1/(i+1)) * sum_{j<=i} relu(q_i.k_j) * v_j
// 512 blocks = 64 slice-pairs (s,127-s) x 8 batches. 8 waves = 2 slices x 4
// j-quarters. S^T via mfma(K,Q); cvt_pk + 8 shfl repack; no in-loop LDS.
__global__ __launch_bounds__(512, 2) void attn_k(
    const ushort* __restrict__ Qp, const ushort* __restrict__ Kp,
    const ushort* __restrict__ Vp, const float* __restrict__ H,
    float* __restrict__ X)
{
    int blk = blockIdx.x;            // pk*8 + b
    int pk = blk >> 3, b = blk & 7;
    int tid = threadIdx.x;
    int w = tid >> 6, l = tid & 63;
    int lr = l & 15, lg = l >> 4;
    int sel  = (w & 1) ^ ((w >> 2) & 1);
    int part = w >> 1;
    int s  = sel ? (127 - pk) : pk;  // 16-row slice index within batch
    int i0 = s * 16;
    int NT = (s >> 1) + 1;           // causal j-tiles of 32
    int j0 = (part * NT) >> 2;
    int j1 = ((part + 1) * NT) >> 2;

    __shared__ float comb[2][5440];

    const ushort* Qt    = Qp + (size_t)(b*128 + s) * 4096 + l*8;
    const ushort* Kbase = Kp + (size_t)(b*128) * 4096 + l*8;
    const ushort* Vbase = Vp + (size_t)(b*64) * 16 * 512 + l*8;

    short8 qb[8];
    #pragma unroll
    for (int kc = 0; kc < 8; ++kc) qb[kc] = *(const short8*)(Qt + kc*512);

    f32x4 oacc[16];
    #pragma unroll
    for (int et = 0; et < 16; ++et) oacc[et] = (f32x4){0.f,0.f,0.f,0.f};

    int ig = i0 + lr;
    for (int jt = j0; jt < j1; ++jt) {
        // coalesced fragment loads: K (2 tiles x 8 kc), V (16 e-tiles)
        const ushort* Kt = Kbase + (size_t)(jt*2) * 4096;
        short8 ka0[8], ka1[8];
        #pragma unroll
        for (int kc = 0; kc < 8; ++kc) {
            ka0[kc] = *(const short8*)(Kt + kc*512);
            ka1[kc] = *(const short8*)(Kt + 4096 + kc*512);
        }
        const ushort* Vt = Vbase + (size_t)(jt*16) * 512;
        short8 vf[16];
        #pragma unroll
        for (int et = 0; et < 16; ++et)
            vf[et] = *(const short8*)(Vt + et*512);
        // QK^T (swapped): c0/c1 hold S^T[j][i]
        f32x4 c0 = {0.f,0.f,0.f,0.f}, c1 = {0.f,0.f,0.f,0.f};
        #pragma unroll
        for (int kc = 0; kc < 8; ++kc) {
            c0 = __builtin_amdgcn_mfma_f32_16x16x32_bf16(ka0[kc], qb[kc], c0, 0,0,0);
            c1 = __builtin_amdgcn_mfma_f32_16x16x32_bf16(ka1[kc], qb[kc], c1, 0,0,0);
        }
        // relu + causal mask (j <= i)
        #pragma unroll
        for (int r = 0; r < 4; ++r) {
            int jg = jt*32 + lg*4 + r;
            c0[r] = (jg <= ig) ? fmaxf(c0[r], 0.f) : 0.f;
            c1[r] = (jg + 16 <= ig) ? fmaxf(c1[r], 0.f) : 0.f;
        }
        // pack to bf16 pairs and repack C-layout -> PV A-frag via shfl
        unsigned u0 = cvtpk(c0[0], c0[1]), u1 = cvtpk(c0[2], c0[3]);
        unsigned u2 = cvtpk(c1[0], c1[1]), u3 = cvtpk(c1[2], c1[3]);
        int srcA = 32*(lg & 1) + lr;
        int srcB = srcA + 16;
        unsigned a0A = __shfl((int)u0, srcA), a1A = __shfl((int)u1, srcA);
        unsigned a0B = __shfl((int)u0, srcB), a1B = __shfl((int)u1, srcB);
        unsigned b0A = __shfl((int)u2, srcA), b1A = __shfl((int)u3, srcA);
        unsigned b0B = __shfl((int)u2, srcB), b1B = __shfl((int)u3, srcB);
        bool lo = (lg < 2);
        union { unsigned u[4]; short8 v; } sv;
        sv.u[0] = lo ? a0A : b0A;
        sv.u[1] = lo ? a1A : b1A;
        sv.u[2] = lo ? a0B : b0B;
        sv.u[3] = lo ? a1B : b1B;
        short8 sa = sv.v;
        // PV: O[16][256] += S @ V_jt
        #pragma unroll
        for (int et = 0; et < 16; ++et)
            oacc[et] = __builtin_amdgcn_mfma_f32_16x16x32_bf16(sa, vf[et], oacc[et], 0,0,0);
    }

    // ---- 4-way combine (parts 1..3 -> LDS) + epilogue by part 0 ----
    float* cb = &comb[sel][0];
    #pragma unroll
    for (int rnd = 1; rnd <= 3; ++rnd) {
        if (part == rnd) {
            #pragma unroll
            for (int et = 0; et < 16; ++et)
                #pragma unroll
                for (int r = 0; r < 4; ++r) {
                    int idx = et*340 + l*5 + r;
                    float v = oacc[et][r];
                    if (rnd == 1) cb[idx] = v; else cb[idx] += v;
                }
        }
        __syncthreads();
    }
    if (part == 0) {
        #pragma unroll
        for (int et = 0; et < 16; ++et)
            #pragma unroll
            for (int r = 0; r < 4; ++r) {
                int irow = i0 + lg*4 + r;
                float o = oacc[et][r] + cb[et*340 + l*5 + r];
                float sc = 1.0f / (float)(irow + 1);
                size_t base = ((size_t)(b*NN + irow))*EE + et*16 + lr;
                X[base] = H[base] + o * sc;
            }
    }
}

// ---------------- LayerNorm: 1 wave per row, fp32 + packed bf16 out ----------
__global__ __launch_bounds__(256) void ln_k(
    const float* __restrict__ Xin, const float* __restrict__ g,
    const float* __restrict__ bta, float* __restrict__ HoutF,
    ushort* __restrict__ HoutB)
{
    int w = threadIdx.x >> 6, l = threadIdx.x & 63;
    size_t row = (size_t)blockIdx.x*4 + w;
    float4 x = *(const float4*)&Xin[row*EE + l*4];
    float s  = x.x + x.y + x.z + x.w;
    float s2 = x.x*x.x + x.y*x.y + x.z*x.z + x.w*x.w;
    #pragma unroll
    for (int off = 1; off < 64; off <<= 1) {
        s  += __shfl_xor(s,  off);
        s2 += __shfl_xor(s2, off);
    }
    float mean = s * (1.0f/256.0f);
    float var  = s2 * (1.0f/256.0f) - mean*mean;
    float inv  = 1.0f / sqrtf(var + 1e-5f);
    float4 gv = *(const float4*)&g[l*4];
    float4 bv = *(const float4*)&bta[l*4];
    float4 y;
    y.x = (x.x - mean)*inv*gv.x + bv.x;
    y.y = (x.y - mean)*inv*gv.y + bv.y;
    y.z = (x.z - mean)*inv*gv.z + bv.z;
    y.w = (x.w - mean)*inv*gv.w + bv.w;
    *(float4*)&HoutF[row*EE + l*4] = y;
    ushort4 yb; yb.x = f2b(y.x); yb.y = f2b(y.y); yb.z = f2b(y.z); yb.w = f2b(y.w);
    *(ushort4*)&HoutB[pk256((int)row, l*4)] = yb;
}

// ---------------- prediction head (even rows only) ----------------
__global__ __launch_bounds__(256) void pred_k(
    const float* __restrict__ H, const float* __restrict__ Wp,
    const float* __restrict__ bp, float* __restrict__ out)
{
    int bt = blockIdx.x;
    int b = bt >> 10, t = bt & 1023;
    size_t row = (size_t)b*NN + 2*t;
    __shared__ float hs[256];
    __shared__ float pr[16][16];
    int tid = threadIdx.x;
    hs[tid] = H[row*EE + tid];
    __syncthreads();
    int c = tid & 15, seg = tid >> 4;
    float p = 0.f;
    if (c < 10) {
        #pragma unroll
        for (int e2 = 0; e2 < 16; ++e2)
            p = fmaf(hs[seg*16 + e2], Wp[(seg*16 + e2)*10 + c], p);
    }
    pr[seg][c] = p;
    __syncthreads();
    if (tid < 10) {
        float sacc = bp[tid];
        #pragma unroll
        for (int k2 = 0; k2 < 16; ++k2) sacc += pr[k2][tid];
        out[(size_t)bt*10 + tid] = sacc;
    }
}

extern "C" void kernel_launch(void* const* d_in, const int* in_sizes, int n_in,
                              void* d_out, int out_size, void* d_ws, size_t ws_size,
                              hipStream_t stream)
{
    const float* action_set = (const float*)d_in[1];
    const float* ctx_act    = (const float*)d_in[2];
    const float* ctx_rew    = (const float*)d_in[3];
    const float* W_embed    = (const float*)d_in[4];
    const float* b_embed    = (const float*)d_in[5];
    const float* wpe        = (const float*)d_in[6];
    const float* Wq         = (const float*)d_in[7];
    const float* Wk         = (const float*)d_in[8];
    const float* Wv         = (const float*)d_in[9];
    const float* ln1g       = (const float*)d_in[10];
    const float* ln1b       = (const float*)d_in[11];
    const float* W1         = (const float*)d_in[12];
    const float* b1         = (const float*)d_in[13];
    const float* W2         = (const float*)d_in[14];
    const float* b2         = (const float*)d_in[15];
    const float* ln2g       = (const float*)d_in[16];
    const float* ln2b       = (const float*)d_in[17];
    const float* Wp         = (const float*)d_in[18];
    const float* bp         = (const float*)d_in[19];
    float* out = (float*)d_out;

    float* ws = (float*)d_ws;
    const size_t SZ = (size_t)BB*NN*EE;   // 4,194,304
    size_t o = 0;
    float*  Hb   = ws;               o += SZ;        // fp32 residual stream
    float*  Xb   = ws + o;           o += SZ;        // fp32 scratch (attn out / ln1 out)
    ushort* Hbf  = (ushort*)(ws+o);  o += SZ/2;      // packed bf16 stream
    ushort* Qp   = (ushort*)(ws+o);  o += SZ/2;      // packed Q; aliased MLP-mid
    ushort* Kpk  = (ushort*)(ws+o);  o += SZ/2;      // packed K
    ushort* Vpk  = (ushort*)(ws+o);  o += SZ/2;      // packed V; aliased ln1-bf16
    ushort* WQKt = (ushort*)(ws+o);  o += 262144;
    ushort* WVt  = (ushort*)(ws+o);  o += 131072;
    ushort* W1t  = (ushort*)(ws+o);  o += 131072;
    ushort* W2t  = (ushort*)(ws+o);  o += 131072;
    float*  BE   = ws + o;

    wprep_k<<<320, 256, 0, stream>>>(Wq, Wk, Wv, W1, W2, WQKt, WVt, W1t, W2t);
    base_even_k<<<BB, 256, 0, stream>>>(action_set, W_embed, b_embed, BE);
    embed_k<<<BB*NN/8, 256, 0, stream>>>(BE, ctx_act, ctx_rew, W_embed, b_embed, wpe, Hb, Hbf);

    for (int l = 0; l < LL; ++l) {
        // fused Q|K GEMM -> Qp / Kpk (packed)
        bgemm_k<0,0,0,3><<<dim3(128, 4), 256, 0, stream>>>(
            Hbf, WQKt + (size_t)l*131072, nullptr, nullptr, Qp, Kpk, 0);
        // V GEMM (row=e, col=token) -> Vpk (packed)
        bgemm_k<0,0,0,2><<<dim3(2, 128), 256, 0, stream>>>(
            WVt + (size_t)l*65536, Hbf, nullptr, nullptr, Vpk, nullptr, 0);
        attn_k<<<512, 512, 0, stream>>>(Qp, Kpk, Vpk, Hb, Xb);
        // ln1: Xb -> Xb (fp32, in-place) + Vpk-region (packed bf16)
        ln_k<<<BB*NN/4, 256, 0, stream>>>(Xb, ln1g + l*EE, ln1b + l*EE, Xb, Vpk);
        // mlp1: relu(ln1 @ W1 + b1) -> Qp-region (packed bf16)
        bgemm_k<1,1,0,1><<<dim3(128, 2), 256, 0, stream>>>(
            Vpk, W1t + (size_t)l*65536, b1 + l*EE, nullptr, Qp, nullptr, 0);
        // mlp2: mid @ W2 + b2 + ln1(fp32) -> Hb (fp32)
        bgemm_k<0,1,1,0><<<dim3(128, 2), 256, 0, stream>>>(
            Qp, W2t + (size_t)l*65536, b2 + l*EE, Xb, Hb, nullptr, 256);
        // ln2: Hb -> Hb (in-place) + Hbf (packed)
        ln_k<<<BB*NN/4, 256, 0, stream>>>(Hb, ln2g + l*EE, ln2b + l*EE, Hb, Hbf);
    }
    pred_k<<<BB*TT, 256, 0, stream>>>(Hb, Wp, bp, out);
}

// Round 6
// 446.298 us; speedup vs baseline: 7.8794x; 1.2105x over previous
//
#include <hip/hip_runtime.h>

// Transformer_67748814127473 — round 5: fused ln1-into-attn, ln2-into-mlp2,
// merged QKV GEMM, 4-way QK chain split + setprio. B=8,T=1024,N=2048,E=256,L=4.

#define BB 8
#define TT 1024
#define NN 2048
#define EE 256
#define LL 4

typedef __attribute__((ext_vector_type(8))) short short8;
typedef __attribute__((ext_vector_type(4))) float f32x4;

__device__ inline ushort f2b(float f) {
    union { float f; unsigned u; } x; x.f = f;
    unsigned u = x.u;
    return (ushort)((u + 0x7fffu + ((u >> 16) & 1u)) >> 16);
}
__device__ inline unsigned cvtpk(float lo, float hi) {
    unsigned r;
    asm volatile("v_cvt_pk_bf16_f32 %0, %1, %2" : "=v"(r) : "v"(lo), "v"(hi));
    return r;
}
// fragment-linear pack for K=256 operands: tile16(row) x kchunk32 -> [lane][8]
__device__ inline size_t pk256(int row, int k) {
    return ((size_t)((row >> 4) * 8 + (k >> 5))) * 512
         + (size_t)((((k >> 3) & 3) * 16 + (row & 15)) * 8 + (k & 7));
}
// V pack: (batch, token n, embed e) -> B-frag linear
__device__ inline size_t vpk_idx(int bb, int nn, int e) {
    return ((size_t)(bb*64 + (nn >> 5)) * 16 + (e >> 4)) * 512
         + (size_t)((((nn >> 3) & 3) * 16 + (e & 15)) * 8 + (nn & 7));
}

// ---------------- weight prep: transpose + cast + frag-pack ----------------
__global__ __launch_bounds__(256) void wprep_k(
    const float* __restrict__ Wq, const float* __restrict__ Wk,
    const float* __restrict__ Wv, const float* __restrict__ W1,
    const float* __restrict__ W2,
    ushort* __restrict__ WQKt, ushort* __restrict__ WVt,
    ushort* __restrict__ W1t, ushort* __restrict__ W2t)
{
    int id = blockIdx.x;          // 320 = 20 matrices x 16 tiles
    int m = id >> 4, t = id & 15;
    int l = m / 5, which = m % 5;
    const float* src; ushort* dst;
    size_t o = (size_t)l * 65536;
    switch (which) {
        case 0: src = Wq + o; dst = WQKt + (size_t)l*131072;          break;
        case 1: src = Wk + o; dst = WQKt + (size_t)l*131072 + 65536;  break;
        case 2: src = Wv + o; dst = WVt + o; break;
        case 3: src = W1 + o; dst = W1t + o; break;
        default: src = W2 + o; dst = W2t + o; break;
    }
    int tk = (t >> 2) * 64;   // k block
    int tn = (t & 3) * 64;    // n block (output col)
    __shared__ ushort T[64][68];
    int tid = threadIdx.x;
    int r = tid >> 4, c4 = (tid & 15) * 4;
    #pragma unroll
    for (int it = 0; it < 4; ++it) {
        int k = r + it*16;
        float4 v = *(const float4*)&src[(size_t)(tk + k)*256 + tn + c4];
        T[k][c4+0] = f2b(v.x); T[k][c4+1] = f2b(v.y);
        T[k][c4+2] = f2b(v.z); T[k][c4+3] = f2b(v.w);
    }
    __syncthreads();
    #pragma unroll
    for (int it = 0; it < 4; ++it) {
        int n = tn + r + it*16;
        int k0 = tk + c4;
        ushort4 ov;
        ov.x = T[c4+0][n-tn]; ov.y = T[c4+1][n-tn];
        ov.z = T[c4+2][n-tn]; ov.w = T[c4+3][n-tn];
        *(ushort4*)&dst[pk256(n, k0)] = ov;
    }
}

// ---------------- per-batch even-row base vector ----------------
__global__ __launch_bounds__(256) void base_even_k(
    const float* __restrict__ aset, const float* __restrict__ We,
    const float* __restrict__ be, float* __restrict__ BE)
{
    int b = blockIdx.x; int e = threadIdx.x;
    __shared__ float as[640];
    for (int i = e; i < 640; i += 256) as[i] = aset[b*640 + i];
    __syncthreads();
    float s = We[651*EE + e] + be[e];
    for (int f = 0; f < 640; ++f) s = fmaf(as[f], We[f*EE + e], s);
    BE[b*EE + e] = s;
}

// ---------------- embedding (8 rows per block), fp32 + packed bf16 ----------
__global__ __launch_bounds__(256) void embed_k(
    const float* __restrict__ BE, const float* __restrict__ ca,
    const float* __restrict__ cr, const float* __restrict__ We,
    const float* __restrict__ be, const float* __restrict__ wpe,
    float* __restrict__ H, ushort* __restrict__ Hbf)
{
    int e = threadIdx.x;
    #pragma unroll
    for (int k = 0; k < 8; ++k) {
        int rb = blockIdx.x * 8 + k;
        int b = rb >> 11, n = rb & (NN-1);
        float h;
        if ((n & 1) == 0) {
            h = BE[b*EE + e];
        } else {
            int t = n >> 1;
            h = We[651*EE + e] + be[e];
            const float* cap = ca + (size_t)(b*TT + t)*10;
            #pragma unroll
            for (int i = 0; i < 10; ++i) h = fmaf(cap[i], We[(640+i)*EE + e], h);
            h = fmaf(cr[b*TT + t], We[650*EE + e], h);
        }
        h = fmaf((float)(n + 1), We[652*EE + e], h);
        h += wpe[(size_t)n*EE + e];
        H[(size_t)rb*EE + e] = h;
        Hbf[pk256(rb, e)] = f2b(h);
    }
}

// ---------------- merged QKV GEMM (packed in, packed out) -------------------
// grid (128, 6): by 0-1 -> Q cols, 2-3 -> K cols, 4-5 -> V (transposed pack).
__global__ __launch_bounds__(256, 2) void qkv_k(
    const ushort* __restrict__ A, const ushort* __restrict__ WQK,
    const ushort* __restrict__ WV,
    ushort* __restrict__ Qo, ushort* __restrict__ Ko, ushort* __restrict__ Vo)
{
    int tid = threadIdx.x;
    int w = tid >> 6, l = tid & 63;
    int lr = l & 15, lg = l >> 4;
    int wr = w >> 1, wc = w & 1;
    int rt0 = blockIdx.x * 8 + wr*4;
    int ct0 = blockIdx.y * 8 + wc*4;
    const ushort* Ap = A + (size_t)rt0*4096 + l*8;
    const ushort* Bp = (blockIdx.y < 4 ? WQK + (size_t)ct0*4096
                                       : WV + (size_t)(ct0-32)*4096) + l*8;
    f32x4 acc[4][4];
    #pragma unroll
    for (int i = 0; i < 4; ++i)
        #pragma unroll
        for (int j = 0; j < 4; ++j) acc[i][j] = (f32x4){0.f,0.f,0.f,0.f};
    #pragma unroll
    for (int kc = 0; kc < 8; ++kc) {
        short8 af[4], bf[4];
        #pragma unroll
        for (int rg = 0; rg < 4; ++rg) af[rg] = *(const short8*)(Ap + (size_t)rg*4096 + kc*512);
        #pragma unroll
        for (int cg = 0; cg < 4; ++cg) bf[cg] = *(const short8*)(Bp + (size_t)cg*4096 + kc*512);
        #pragma unroll
        for (int rg = 0; rg < 4; ++rg)
            #pragma unroll
            for (int cg = 0; cg < 4; ++cg)
                acc[rg][cg] = __builtin_amdgcn_mfma_f32_16x16x32_bf16(af[rg], bf[cg], acc[rg][cg], 0,0,0);
    }
    #pragma unroll
    for (int rg = 0; rg < 4; ++rg)
        #pragma unroll
        for (int cg = 0; cg < 4; ++cg)
            #pragma unroll
            for (int r = 0; r < 4; ++r) {
                int row = rt0*16 + rg*16 + lg*4 + r;
                int col = ct0*16 + cg*16 + lr;
                ushort xv = f2b(acc[rg][cg][r]);
                if (col < 256)      Qo[pk256(row, col)] = xv;
                else if (col < 512) Ko[pk256(row, col - 256)] = xv;
                else {
                    int e = col - 512, bb = row >> 11, nn = row & (NN-1);
                    Vo[vpk_idx(bb, nn, e)] = xv;
                }
            }
}

// ---------------- bf16 MFMA GEMM (mlp1): relu(A@W1^T + b1) -> packed --------
__global__ __launch_bounds__(256, 2) void mlp1_k(
    const ushort* __restrict__ A, const ushort* __restrict__ Bw,
    const float* __restrict__ bias, ushort* __restrict__ Cv)
{
    int tid = threadIdx.x;
    int w = tid >> 6, l = tid & 63;
    int lr = l & 15, lg = l >> 4;
    int wr = w >> 1, wc = w & 1;
    int rt0 = blockIdx.x * 8 + wr*4;
    int ct0 = blockIdx.y * 8 + wc*4;
    const ushort* Ap = A  + (size_t)rt0*4096 + l*8;
    const ushort* Bp = Bw + (size_t)ct0*4096 + l*8;
    f32x4 acc[4][4];
    #pragma unroll
    for (int i = 0; i < 4; ++i)
        #pragma unroll
        for (int j = 0; j < 4; ++j) acc[i][j] = (f32x4){0.f,0.f,0.f,0.f};
    #pragma unroll
    for (int kc = 0; kc < 8; ++kc) {
        short8 af[4], bf[4];
        #pragma unroll
        for (int rg = 0; rg < 4; ++rg) af[rg] = *(const short8*)(Ap + (size_t)rg*4096 + kc*512);
        #pragma unroll
        for (int cg = 0; cg < 4; ++cg) bf[cg] = *(const short8*)(Bp + (size_t)cg*4096 + kc*512);
        #pragma unroll
        for (int rg = 0; rg < 4; ++rg)
            #pragma unroll
            for (int cg = 0; cg < 4; ++cg)
                acc[rg][cg] = __builtin_amdgcn_mfma_f32_16x16x32_bf16(af[rg], bf[cg], acc[rg][cg], 0,0,0);
    }
    #pragma unroll
    for (int rg = 0; rg < 4; ++rg)
        #pragma unroll
        for (int cg = 0; cg < 4; ++cg)
            #pragma unroll
            for (int r = 0; r < 4; ++r) {
                int row = rt0*16 + rg*16 + lg*4 + r;
                int col = ct0*16 + cg*16 + lr;
                float x = fmaxf(acc[rg][cg][r] + bias[col], 0.f);
                Cv[pk256(row, col)] = f2b(x);
            }
}

// ---------------- mlp2 + residual + ln2 fused -------------------------------
// grid 512: block = 32 rows x 256 cols, 4 waves (each 32x64).
// Hout = LN(mid@W2^T + b2 + Res); also packed bf16 copy.
__global__ __launch_bounds__(256, 2) void mlp2ln_k(
    const ushort* __restrict__ A, const ushort* __restrict__ Bw,
    const float* __restrict__ bias, const float* __restrict__ Res,
    const float* __restrict__ g, const float* __restrict__ bt,
    float* __restrict__ Hout, ushort* __restrict__ Hpk)
{
    int tid = threadIdx.x;
    int w = tid >> 6, l = tid & 63;
    int lr = l & 15, lg = l >> 4;
    int rt0 = blockIdx.x * 2;     // 32 rows
    int ct0 = w * 4;              // 64 cols per wave
    const ushort* Ap = A  + (size_t)rt0*4096 + l*8;
    const ushort* Bp = Bw + (size_t)ct0*4096 + l*8;
    f32x4 acc[2][4];
    #pragma unroll
    for (int i = 0; i < 2; ++i)
        #pragma unroll
        for (int j = 0; j < 4; ++j) acc[i][j] = (f32x4){0.f,0.f,0.f,0.f};
    #pragma unroll
    for (int kc = 0; kc < 8; ++kc) {
        short8 a0 = *(const short8*)(Ap + kc*512);
        short8 a1 = *(const short8*)(Ap + 4096 + kc*512);
        short8 bf[4];
        #pragma unroll
        for (int cg = 0; cg < 4; ++cg) bf[cg] = *(const short8*)(Bp + (size_t)cg*4096 + kc*512);
        #pragma unroll
        for (int cg = 0; cg < 4; ++cg) {
            acc[0][cg] = __builtin_amdgcn_mfma_f32_16x16x32_bf16(a0, bf[cg], acc[0][cg], 0,0,0);
            acc[1][cg] = __builtin_amdgcn_mfma_f32_16x16x32_bf16(a1, bf[cg], acc[1][cg], 0,0,0);
        }
    }
    // epilogue: + bias + residual, per-row stats
    __shared__ float red[32][4][2];
    float sm[2][4] = {}, sq[2][4] = {};
    #pragma unroll
    for (int rg = 0; rg < 2; ++rg)
        #pragma unroll
        for (int cg = 0; cg < 4; ++cg)
            #pragma unroll
            for (int r = 0; r < 4; ++r) {
                int grow = blockIdx.x*32 + rg*16 + lg*4 + r;
                int col = w*64 + cg*16 + lr;
                float v = acc[rg][cg][r] + bias[col] + Res[(size_t)grow*EE + col];
                acc[rg][cg][r] = v;
                sm[rg][r] += v; sq[rg][r] += v*v;
            }
    #pragma unroll
    for (int off = 1; off < 16; off <<= 1)
        #pragma unroll
        for (int rg = 0; rg < 2; ++rg)
            #pragma unroll
            for (int r = 0; r < 4; ++r) {
                sm[rg][r] += __shfl_xor(sm[rg][r], off);
                sq[rg][r] += __shfl_xor(sq[rg][r], off);
            }
    if (lr == 0) {
        #pragma unroll
        for (int rg = 0; rg < 2; ++rg)
            #pragma unroll
            for (int r = 0; r < 4; ++r) {
                int rl = rg*16 + lg*4 + r;
                red[rl][w][0] = sm[rg][r];
                red[rl][w][1] = sq[rg][r];
            }
    }
    __syncthreads();
    #pragma unroll
    for (int rg = 0; rg < 2; ++rg)
        #pragma unroll
        for (int r = 0; r < 4; ++r) {
            int rl = rg*16 + lg*4 + r;
            float S  = red[rl][0][0] + red[rl][1][0] + red[rl][2][0] + red[rl][3][0];
            float S2 = red[rl][0][1] + red[rl][1][1] + red[rl][2][1] + red[rl][3][1];
            float mean = S * (1.0f/256.0f);
            float var  = S2 * (1.0f/256.0f) - mean*mean;
            float inv  = 1.0f / sqrtf(var + 1e-5f);
            int grow = blockIdx.x*32 + rl;
            #pragma unroll
            for (int cg = 0; cg < 4; ++cg) {
                int col = w*64 + cg*16 + lr;
                float y = (acc[rg][cg][r] - mean) * inv * g[col] + bt[col];
                Hout[(size_t)grow*EE + col] = y;
                Hpk[pk256(grow, col)] = f2b(y);
            }
        }
}

// ---------------- register-only-S causal relu-attention + fused ln1 ---------
// Xout = LN1(H + (1/(i+1)) * sum_{j<=i} relu(q_i.k_j) v_j); also packed bf16.
__global__ __launch_bounds__(512, 2) void attn_k(
    const ushort* __restrict__ Qp, const ushort* __restrict__ Kp,
    const ushort* __restrict__ Vp, const float* __restrict__ H,
    const float* __restrict__ g, const float* __restrict__ bt,
    float* __restrict__ Xout, ushort* __restrict__ Lpk)
{
    int blk = blockIdx.x;            // pk*8 + b
    int pk = blk >> 3, b = blk & 7;
    int tid = threadIdx.x;
    int w = tid >> 6, l = tid & 63;
    int lr = l & 15, lg = l >> 4;
    int sel  = (w & 1) ^ ((w >> 2) & 1);
    int part = w >> 1;
    int s  = sel ? (127 - pk) : pk;  // 16-row slice index within batch
    int i0 = s * 16;
    int NT = (s >> 1) + 1;           // causal j-tiles of 32
    int j0 = (part * NT) >> 2;
    int j1 = ((part + 1) * NT) >> 2;

    __shared__ float comb[2][5440];

    const ushort* Qt    = Qp + (size_t)(b*128 + s) * 4096 + l*8;
    const ushort* Kbase = Kp + (size_t)(b*128) * 4096 + l*8;
    const ushort* Vbase = Vp + (size_t)(b*64) * 16 * 512 + l*8;

    short8 qb[8];
    #pragma unroll
    for (int kc = 0; kc < 8; ++kc) qb[kc] = *(const short8*)(Qt + kc*512);

    f32x4 oacc[16];
    #pragma unroll
    for (int et = 0; et < 16; ++et) oacc[et] = (f32x4){0.f,0.f,0.f,0.f};

    int ig = i0 + lr;
    for (int jt = j0; jt < j1; ++jt) {
        const ushort* Kt = Kbase + (size_t)(jt*2) * 4096;
        short8 ka0[8], ka1[8];
        #pragma unroll
        for (int kc = 0; kc < 8; ++kc) {
            ka0[kc] = *(const short8*)(Kt + kc*512);
            ka1[kc] = *(const short8*)(Kt + 4096 + kc*512);
        }
        const ushort* Vt = Vbase + (size_t)(jt*16) * 512;
        short8 vf[16];
        #pragma unroll
        for (int et = 0; et < 16; ++et)
            vf[et] = *(const short8*)(Vt + et*512);
        // QK^T (swapped), 4 independent chains
        f32x4 c0a = {0.f,0.f,0.f,0.f}, c0b = {0.f,0.f,0.f,0.f};
        f32x4 c1a = {0.f,0.f,0.f,0.f}, c1b = {0.f,0.f,0.f,0.f};
        #pragma unroll
        for (int kc = 0; kc < 8; kc += 2) {
            c0a = __builtin_amdgcn_mfma_f32_16x16x32_bf16(ka0[kc],   qb[kc],   c0a, 0,0,0);
            c0b = __builtin_amdgcn_mfma_f32_16x16x32_bf16(ka0[kc+1], qb[kc+1], c0b, 0,0,0);
            c1a = __builtin_amdgcn_mfma_f32_16x16x32_bf16(ka1[kc],   qb[kc],   c1a, 0,0,0);
            c1b = __builtin_amdgcn_mfma_f32_16x16x32_bf16(ka1[kc+1], qb[kc+1], c1b, 0,0,0);
        }
        f32x4 c0 = c0a + c0b, c1 = c1a + c1b;
        // relu + causal mask (j <= i)
        #pragma unroll
        for (int r = 0; r < 4; ++r) {
            int jg = jt*32 + lg*4 + r;
            c0[r] = (jg <= ig) ? fmaxf(c0[r], 0.f) : 0.f;
            c1[r] = (jg + 16 <= ig) ? fmaxf(c1[r], 0.f) : 0.f;
        }
        // pack to bf16 pairs and repack C-layout -> PV A-frag via shfl
        unsigned u0 = cvtpk(c0[0], c0[1]), u1 = cvtpk(c0[2], c0[3]);
        unsigned u2 = cvtpk(c1[0], c1[1]), u3 = cvtpk(c1[2], c1[3]);
        int srcA = 32*(lg & 1) + lr;
        int srcB = srcA + 16;
        unsigned a0A = __shfl((int)u0, srcA), a1A = __shfl((int)u1, srcA);
        unsigned a0B = __shfl((int)u0, srcB), a1B = __shfl((int)u1, srcB);
        unsigned b0A = __shfl((int)u2, srcA), b1A = __shfl((int)u3, srcA);
        unsigned b0B = __shfl((int)u2, srcB), b1B = __shfl((int)u3, srcB);
        bool lo = (lg < 2);
        union { unsigned u[4]; short8 v; } sv;
        sv.u[0] = lo ? a0A : b0A;
        sv.u[1] = lo ? a1A : b1A;
        sv.u[2] = lo ? a0B : b0B;
        sv.u[3] = lo ? a1B : b1B;
        short8 sa = sv.v;
        // PV: O[16][256] += S @ V_jt
        __builtin_amdgcn_s_setprio(1);
        #pragma unroll
        for (int et = 0; et < 16; ++et)
            oacc[et] = __builtin_amdgcn_mfma_f32_16x16x32_bf16(sa, vf[et], oacc[et], 0,0,0);
        __builtin_amdgcn_s_setprio(0);
    }

    // ---- 4-way combine (parts 1..3 -> LDS) ----
    float* cb = &comb[sel][0];
    #pragma unroll
    for (int rnd = 1; rnd <= 3; ++rnd) {
        if (part == rnd) {
            #pragma unroll
            for (int et = 0; et < 16; ++et)
                #pragma unroll
                for (int r = 0; r < 4; ++r) {
                    int idx = et*340 + l*5 + r;
                    float v = oacc[et][r];
                    if (rnd == 1) cb[idx] = v; else cb[idx] += v;
                }
        }
        __syncthreads();
    }
    // ---- epilogue by part 0: residual + scale + LN1, dual output ----
    if (part == 0) {
        float sm[4] = {0.f,0.f,0.f,0.f}, sq[4] = {0.f,0.f,0.f,0.f};
        #pragma unroll
        for (int et = 0; et < 16; ++et)
            #pragma unroll
            for (int r = 0; r < 4; ++r) {
                int irow = i0 + lg*4 + r;
                size_t base = ((size_t)(b*NN + irow))*EE + et*16 + lr;
                float x = H[base] + (oacc[et][r] + cb[et*340 + l*5 + r])
                                    * (1.0f / (float)(irow + 1));
                oacc[et][r] = x;
                sm[r] += x; sq[r] += x*x;
            }
        #pragma unroll
        for (int off = 1; off < 16; off <<= 1)
            #pragma unroll
            for (int r = 0; r < 4; ++r) {
                sm[r] += __shfl_xor(sm[r], off);
                sq[r] += __shfl_xor(sq[r], off);
            }
        float mean[4], inv[4];
        #pragma unroll
        for (int r = 0; r < 4; ++r) {
            mean[r] = sm[r] * (1.0f/256.0f);
            float var = sq[r] * (1.0f/256.0f) - mean[r]*mean[r];
            inv[r] = 1.0f / sqrtf(var + 1e-5f);
        }
        #pragma unroll
        for (int et = 0; et < 16; ++et) {
            int col = et*16 + lr;
            float gv = g[col], bv = bt[col];
            #pragma unroll
            for (int r = 0; r < 4; ++r) {
                int irow = i0 + lg*4 + r;
                size_t base = ((size_t)(b*NN + irow))*EE + col;
                float y = (oacc[et][r] - mean[r]) * inv[r] * gv + bv;
                Xout[base] = y;
                Lpk[pk256(b*NN + irow, col)] = f2b(y);
            }
        }
    }
}

// ---------------- prediction head (even rows only) ----------------
__global__ __launch_bounds__(256) void pred_k(
    const float* __restrict__ H, const float* __restrict__ Wp,
    const float* __restrict__ bp, float* __restrict__ out)
{
    int bt = blockIdx.x;
    int b = bt >> 10, t = bt & 1023;
    size_t row = (size_t)b*NN + 2*t;
    __shared__ float hs[256];
    __shared__ float pr[16][16];
    int tid = threadIdx.x;
    hs[tid] = H[row*EE + tid];
    __syncthreads();
    int c = tid & 15, seg = tid >> 4;
    float p = 0.f;
    if (c < 10) {
        #pragma unroll
        for (int e2 = 0; e2 < 16; ++e2)
            p = fmaf(hs[seg*16 + e2], Wp[(seg*16 + e2)*10 + c], p);
    }
    pr[seg][c] = p;
    __syncthreads();
    if (tid < 10) {
        float sacc = bp[tid];
        #pragma unroll
        for (int k2 = 0; k2 < 16; ++k2) sacc += pr[k2][tid];
        out[(size_t)bt*10 + tid] = sacc;
    }
}

extern "C" void kernel_launch(void* const* d_in, const int* in_sizes, int n_in,
                              void* d_out, int out_size, void* d_ws, size_t ws_size,
                              hipStream_t stream)
{
    const float* action_set = (const float*)d_in[1];
    const float* ctx_act    = (const float*)d_in[2];
    const float* ctx_rew    = (const float*)d_in[3];
    const float* W_embed    = (const float*)d_in[4];
    const float* b_embed    = (const float*)d_in[5];
    const float* wpe        = (const float*)d_in[6];
    const float* Wq         = (const float*)d_in[7];
    const float* Wk         = (const float*)d_in[8];
    const float* Wv         = (const float*)d_in[9];
    const float* ln1g       = (const float*)d_in[10];
    const float* ln1b       = (const float*)d_in[11];
    const float* W1         = (const float*)d_in[12];
    const float* b1         = (const float*)d_in[13];
    const float* W2         = (const float*)d_in[14];
    const float* b2         = (const float*)d_in[15];
    const float* ln2g       = (const float*)d_in[16];
    const float* ln2b       = (const float*)d_in[17];
    const float* Wp         = (const float*)d_in[18];
    const float* bp         = (const float*)d_in[19];
    float* out = (float*)d_out;

    float* ws = (float*)d_ws;
    const size_t SZ = (size_t)BB*NN*EE;   // 4,194,304
    size_t o = 0;
    float*  Hb   = ws;               o += SZ;        // fp32 residual stream
    float*  Xb   = ws + o;           o += SZ;        // fp32 ln1 output
    ushort* Hbf  = (ushort*)(ws+o);  o += SZ/2;      // packed bf16 stream / ln1-packed
    ushort* Qp   = (ushort*)(ws+o);  o += SZ/2;      // packed Q; aliased MLP-mid
    ushort* Kpk  = (ushort*)(ws+o);  o += SZ/2;      // packed K
    ushort* Vpk  = (ushort*)(ws+o);  o += SZ/2;      // packed V
    ushort* WQKt = (ushort*)(ws+o);  o += 262144;
    ushort* WVt  = (ushort*)(ws+o);  o += 131072;
    ushort* W1t  = (ushort*)(ws+o);  o += 131072;
    ushort* W2t  = (ushort*)(ws+o);  o += 131072;
    float*  BE   = ws + o;

    wprep_k<<<320, 256, 0, stream>>>(Wq, Wk, Wv, W1, W2, WQKt, WVt, W1t, W2t);
    base_even_k<<<BB, 256, 0, stream>>>(action_set, W_embed, b_embed, BE);
    embed_k<<<BB*NN/8, 256, 0, stream>>>(BE, ctx_act, ctx_rew, W_embed, b_embed, wpe, Hb, Hbf);

    for (int l = 0; l < LL; ++l) {
        qkv_k<<<dim3(128, 6), 256, 0, stream>>>(
            Hbf, WQKt + (size_t)l*131072, WVt + (size_t)l*65536, Qp, Kpk, Vpk);
        // attn + residual + ln1 -> Xb (fp32), Hbf (packed; dead input, safe)
        attn_k<<<512, 512, 0, stream>>>(
            Qp, Kpk, Vpk, Hb, ln1g + l*EE, ln1b + l*EE, Xb, Hbf);
        // mlp1: relu(ln1 @ W1 + b1) -> Qp (packed mid)
        mlp1_k<<<dim3(128, 2), 256, 0, stream>>>(
            Hbf, W1t + (size_t)l*65536, b1 + l*EE, Qp);
        // mlp2 + residual(Xb) + ln2 -> Hb (fp32) + Hbf (packed stream)
        mlp2ln_k<<<512, 256, 0, stream>>>(
            Qp, W2t + (size_t)l*65536, b2 + l*EE, Xb,
            ln2g + l*EE, ln2b + l*EE, Hb, Hbf);
    }
    pred_k<<<BB*TT, 256, 0, stream>>>(Hb, Wp, bp, out);
}